// Round 1
// baseline (520.991 us; speedup 1.0000x reference)
//
#include <hip/hip_runtime.h>
#include <math.h>

constexpr int B_ = 64;
constexpr int N_ = 1000;
constexpr int D_ = 128;
constexpr int E_ = 20000;
constexpr int BN_TOT = B_ * N_;
constexpr float BN_EPS = 1e-5f;
constexpr float NEG_SLOPE = 0.2f;

// ---------------- small precompute kernels ----------------

// zero the scratch region used by counters: offs(1024) + cursor(1024) + bn_sum(128) + bn_sumsq(128)
__global__ void k_zero(int* base) {
    int i = threadIdx.x;
    for (int k = i; k < 2304; k += 256) base[k] = 0;
}

// per-node embedding scores: eemi[n] = emb[n]·att_em_i, eemj[n] = emb[n]·att_em_j
__global__ __launch_bounds__(64) void k_emb_scores(const float* __restrict__ emb,
                                                   const float* __restrict__ att_em_i,
                                                   const float* __restrict__ att_em_j,
                                                   float* __restrict__ eemi,
                                                   float* __restrict__ eemj) {
    int n = blockIdx.x;
    int lane = threadIdx.x;
    const float* er = emb + (size_t)n * D_;
    float e0 = er[lane], e1 = er[lane + 64];
    float si = e0 * att_em_i[lane] + e1 * att_em_i[lane + 64];
    float sj = e0 * att_em_j[lane] + e1 * att_em_j[lane + 64];
    for (int off = 32; off > 0; off >>= 1) {
        si += __shfl_down(si, off);
        sj += __shfl_down(sj, off);
    }
    if (lane == 0) { eemi[n] = si; eemj[n] = sj; }
}

// fold f_w2 + out_w: g[j] = sum_k out_w[k]*f_w2[k][j];  c0 = out_w·f_b2 + out_b
__global__ void k_gvec(const float* __restrict__ f_w2, const float* __restrict__ f_b2,
                       const float* __restrict__ out_w, const float* __restrict__ out_b,
                       float* __restrict__ g, float* __restrict__ c0) {
    int j = threadIdx.x;  // 128
    float s = 0.f;
    for (int k = 0; k < D_; ++k) s += out_w[k] * f_w2[k * D_ + j];
    g[j] = s;
    if (j == 0) {
        float c = out_b[0];
        for (int k = 0; k < D_; ++k) c += out_w[k] * f_b2[k];
        *c0 = c;
    }
}

// ---------------- dual GEMM: x = data@lin_w.T ; t = data@v_w.T + v_b ----------------
// 256 threads: tid<128 -> lin_w column d, tid>=128 -> v_w column d.
// Each thread keeps its 128-float weight row in registers; 8 rows of data staged in LDS.
__global__ __launch_bounds__(256) void k_dual_gemm(const float* __restrict__ data,
                                                   const float* __restrict__ lin_w,
                                                   const float* __restrict__ v_w,
                                                   const float* __restrict__ v_b,
                                                   float* __restrict__ x,
                                                   float* __restrict__ tmat) {
    const int tid = threadIdx.x;
    const int d = tid & 127;
    const int which = tid >> 7;  // 0: x, 1: t
    const float* wrow = (which ? v_w : lin_w) + (size_t)d * D_;
    float w[D_];
#pragma unroll
    for (int k = 0; k < D_; ++k) w[k] = wrow[k];
    const float bias = which ? v_b[d] : 0.f;
    __shared__ float sdata[8][D_];
    const int ntiles = BN_TOT / 8;
    for (int tile = blockIdx.x; tile < ntiles; tile += gridDim.x) {
        const int row0 = tile * 8;
        const float* src = data + (size_t)row0 * D_;
        for (int i = tid; i < 8 * D_; i += 256) sdata[i >> 7][i & 127] = src[i];
        __syncthreads();
        float acc[8];
#pragma unroll
        for (int r = 0; r < 8; ++r) acc[r] = bias;
#pragma unroll
        for (int k = 0; k < D_; ++k) {
            const float wk = w[k];
#pragma unroll
            for (int r = 0; r < 8; ++r) acc[r] += sdata[r][k] * wk;
        }
        float* dst = (which ? tmat : x) + (size_t)row0 * D_ + d;
#pragma unroll
        for (int r = 0; r < 8; ++r) dst[(size_t)r * D_] = acc[r];
        __syncthreads();
    }
}

// ---------------- node attention scores: ni = x·att_i + eemi[n], nj = x·att_j + eemj[n] ----------------
__global__ __launch_bounds__(256) void k_scores(const float* __restrict__ x,
                                                const float* __restrict__ att_i,
                                                const float* __restrict__ att_j,
                                                const float* __restrict__ eemi,
                                                const float* __restrict__ eemj,
                                                float* __restrict__ ni, float* __restrict__ nj) {
    const int wid = threadIdx.x >> 6;
    const int lane = threadIdx.x & 63;
    const int row = blockIdx.x * 4 + wid;
    const float* xr = x + (size_t)row * D_;
    float x0 = xr[lane], x1 = xr[lane + 64];
    float si = x0 * att_i[lane] + x1 * att_i[lane + 64];
    float sj = x0 * att_j[lane] + x1 * att_j[lane + 64];
    for (int off = 32; off > 0; off >>= 1) {
        si += __shfl_down(si, off);
        sj += __shfl_down(sj, off);
    }
    if (lane == 0) {
        int n = row % N_;
        ni[row] = si + eemi[n];
        nj[row] = sj + eemj[n];
    }
}

// ---------------- CSR build (per dst node, shared across batches) ----------------
__global__ void k_count(const int* __restrict__ ei, int* __restrict__ offs) {
    int e = blockIdx.x * blockDim.x + threadIdx.x;
    if (e < E_) atomicAdd(&offs[ei[E_ + e] + 1], 1);  // ei row1 = dst
}

__global__ __launch_bounds__(1024) void k_scan(int* __restrict__ offs) {
    __shared__ int s[N_ + 1];
    int tid = threadIdx.x;
    if (tid <= N_) s[tid] = offs[tid];
    __syncthreads();
    for (int off = 1; off <= N_; off <<= 1) {
        int v = 0;
        if (tid <= N_) { v = s[tid]; if (tid >= off) v += s[tid - off]; }
        __syncthreads();
        if (tid <= N_) s[tid] = v;
        __syncthreads();
    }
    if (tid <= N_) offs[tid] = s[tid];
}

__global__ void k_scatter(const int* __restrict__ ei, const int* __restrict__ offs,
                          int* __restrict__ cursor, int* __restrict__ csr_src) {
    int e = blockIdx.x * blockDim.x + threadIdx.x;
    if (e < E_) {
        int dn = ei[E_ + e];
        int pos = offs[dn] + atomicAdd(&cursor[dn], 1);
        csr_src[pos] = ei[e];  // src node
    }
}

// ---------------- segment softmax + aggregation: one block per (b, dst-node) ----------------
__global__ __launch_bounds__(128) void k_edge_agg(const float* __restrict__ x,
                                                  const float* __restrict__ ni,
                                                  const float* __restrict__ nj,
                                                  const int* __restrict__ offs,
                                                  const int* __restrict__ csr_src,
                                                  const float* __restrict__ gnn_bias,
                                                  float* __restrict__ agg) {
    const int bid = blockIdx.x;        // = b*N + i
    const int b = bid / N_;
    const int i = bid - b * N_;
    const int base = b * N_;
    const int d = threadIdx.x;
    const int e0 = offs[i], e1 = offs[i + 1];
    const float nii = ni[bid];
    float aself = nii + nj[bid];
    aself = aself >= 0.f ? aself : NEG_SLOPE * aself;
    float amax = aself;
    for (int e = e0; e < e1; ++e) {
        int s = csr_src[e];
        float a = nii + nj[base + s];
        a = a >= 0.f ? a : NEG_SLOPE * a;
        amax = fmaxf(amax, a);
    }
    float denom = __expf(aself - amax);
    float acc = denom * x[(size_t)bid * D_ + d];
    for (int e = e0; e < e1; ++e) {
        int s = csr_src[e];
        float a = nii + nj[base + s];
        a = a >= 0.f ? a : NEG_SLOPE * a;
        float wgt = __expf(a - amax);
        denom += wgt;
        acc += wgt * x[(size_t)(base + s) * D_ + d];
    }
    agg[(size_t)bid * D_ + d] = acc / denom + gnn_bias[d];
}

// ---------------- BatchNorm statistics ----------------
__global__ __launch_bounds__(128) void k_bn_stats(const float* __restrict__ agg,
                                                  float* __restrict__ bn_sum,
                                                  float* __restrict__ bn_sumsq) {
    const int d = threadIdx.x;
    const int rows_per = (BN_TOT + gridDim.x - 1) / gridDim.x;
    const int r0 = blockIdx.x * rows_per;
    const int r1 = min(r0 + rows_per, BN_TOT);
    float s = 0.f, sq = 0.f;
    for (int r = r0; r < r1; ++r) {
        float v = agg[(size_t)r * D_ + d];
        s += v;
        sq += v * v;
    }
    atomicAdd(&bn_sum[d], s);
    atomicAdd(&bn_sumsq[d], sq);
}

__global__ void k_bn_fin(const float* __restrict__ bn_sum, const float* __restrict__ bn_sumsq,
                         const float* __restrict__ gamma, const float* __restrict__ beta,
                         float* __restrict__ scale, float* __restrict__ shift) {
    int d = threadIdx.x;
    float mu = bn_sum[d] * (1.f / BN_TOT);
    float var = bn_sumsq[d] * (1.f / BN_TOT) - mu * mu;
    float sc = gamma[d] * rsqrtf(var + BN_EPS);
    scale[d] = sc;
    shift[d] = beta[d] - mu * sc;
}

// ---------------- fusion MLP (folded output layer) ----------------
// out[r] = g · relu( W1 @ [bn_relu(agg[r]) | t[r]] + b1 ) + c0
__global__ __launch_bounds__(256) void k_fusion(const float* __restrict__ agg,
                                                const float* __restrict__ tmat,
                                                const float* __restrict__ f_w1,
                                                const float* __restrict__ f_b1,
                                                const float* __restrict__ scale,
                                                const float* __restrict__ shift,
                                                const float* __restrict__ g,
                                                const float* __restrict__ c0p,
                                                float* __restrict__ out) {
    const int tid = threadIdx.x;
    const int j = tid & 127;
    const int half = tid >> 7;
    const float* wrow = f_w1 + (size_t)j * (2 * D_) + half * D_;
    float w[D_];
#pragma unroll
    for (int k = 0; k < D_; ++k) w[k] = wrow[k];
    __shared__ float comb[4][2 * D_];
    __shared__ float hpart[4][2][D_];
    const float c0 = *c0p;
    const int ntiles = BN_TOT / 4;
    for (int tile = blockIdx.x; tile < ntiles; tile += gridDim.x) {
        const int row0 = tile * 4;
        for (int i = tid; i < 4 * 2 * D_; i += 256) {
            int r = i >> 8;
            int c = i & 255;
            float v;
            if (c < D_) {
                float a = agg[(size_t)(row0 + r) * D_ + c];
                v = fmaxf(scale[c] * a + shift[c], 0.f);
            } else {
                v = tmat[(size_t)(row0 + r) * D_ + (c - D_)];
            }
            comb[r][c] = v;
        }
        __syncthreads();
#pragma unroll
        for (int r = 0; r < 4; ++r) {
            float acc = 0.f;
#pragma unroll
            for (int k = 0; k < D_; ++k) acc += comb[r][half * D_ + k] * w[k];
            hpart[r][half][j] = acc;
        }
        __syncthreads();
        {
            const int gg = tid >> 6;   // group handles row gg
            const int lane = tid & 63;
            float h1 = hpart[gg][0][lane] + hpart[gg][1][lane] + f_b1[lane];
            float h2 = hpart[gg][0][lane + 64] + hpart[gg][1][lane + 64] + f_b1[lane + 64];
            h1 = fmaxf(h1, 0.f);
            h2 = fmaxf(h2, 0.f);
            float p = h1 * g[lane] + h2 * g[lane + 64];
            for (int off = 32; off > 0; off >>= 1) p += __shfl_down(p, off);
            if (lane == 0) out[row0 + gg] = p + c0;
        }
        __syncthreads();
    }
}

// ---------------- launch ----------------
extern "C" void kernel_launch(void* const* d_in, const int* in_sizes, int n_in,
                              void* d_out, int out_size, void* d_ws, size_t ws_size,
                              hipStream_t stream) {
    const float* data     = (const float*)d_in[0];
    const int*   ei       = (const int*)d_in[1];
    const float* emb      = (const float*)d_in[2];
    const float* lin_w    = (const float*)d_in[3];
    const float* att_i    = (const float*)d_in[4];
    const float* att_j    = (const float*)d_in[5];
    const float* att_em_i = (const float*)d_in[6];
    const float* att_em_j = (const float*)d_in[7];
    const float* gnn_bias = (const float*)d_in[8];
    const float* bn_gamma = (const float*)d_in[9];
    const float* bn_beta  = (const float*)d_in[10];
    // 11..14 (q_w,q_b,k_w,k_b) and 17 (temperature) are dead: W=1 -> softmax over 1 element -> attn==1
    const float* v_w      = (const float*)d_in[15];
    const float* v_b      = (const float*)d_in[16];
    const float* f_w1     = (const float*)d_in[18];
    const float* f_b1     = (const float*)d_in[19];
    const float* f_w2     = (const float*)d_in[20];
    const float* f_b2     = (const float*)d_in[21];
    const float* out_w    = (const float*)d_in[22];
    const float* out_b    = (const float*)d_in[23];
    float* out = (float*)d_out;

    float* ws = (float*)d_ws;
    float* x      = ws;                                 // BN*D
    float* tmat   = x + (size_t)BN_TOT * D_;            // BN*D
    float* agg    = tmat + (size_t)BN_TOT * D_;         // BN*D
    float* ni     = agg + (size_t)BN_TOT * D_;          // BN
    float* nj     = ni + BN_TOT;                        // BN
    float* eemi   = nj + BN_TOT;                        // N
    float* eemj   = eemi + N_;                          // N
    float* g      = eemj + N_;                          // D
    float* c0     = g + D_;                             // 1 (pad 8)
    float* scale  = c0 + 8;                             // D
    float* shift  = scale + D_;                         // D
    int* offs     = (int*)(shift + D_);                 // 1024 slot (N+1 used)  [zeroed]
    int* cursor   = offs + 1024;                        // 1024 slot (N used)    [zeroed]
    float* bn_sum = (float*)(cursor + 1024);            // D                     [zeroed]
    float* bn_sq  = bn_sum + D_;                        // D                     [zeroed]
    int* csr_src  = (int*)(bn_sq + D_);                 // E

    k_zero<<<1, 256, 0, stream>>>(offs);
    k_emb_scores<<<N_, 64, 0, stream>>>(emb, att_em_i, att_em_j, eemi, eemj);
    k_gvec<<<1, 128, 0, stream>>>(f_w2, f_b2, out_w, out_b, g, c0);
    k_dual_gemm<<<512, 256, 0, stream>>>(data, lin_w, v_w, v_b, x, tmat);
    k_scores<<<BN_TOT / 4, 256, 0, stream>>>(x, att_i, att_j, eemi, eemj, ni, nj);
    k_count<<<(E_ + 255) / 256, 256, 0, stream>>>(ei, offs);
    k_scan<<<1, 1024, 0, stream>>>(offs);
    k_scatter<<<(E_ + 255) / 256, 256, 0, stream>>>(ei, offs, cursor, csr_src);
    k_edge_agg<<<BN_TOT, 128, 0, stream>>>(x, ni, nj, offs, csr_src, gnn_bias, agg);
    k_bn_stats<<<256, 128, 0, stream>>>(agg, bn_sum, bn_sq);
    k_bn_fin<<<1, 128, 0, stream>>>(bn_sum, bn_sq, bn_gamma, bn_beta, scale, shift);
    k_fusion<<<512, 256, 0, stream>>>(agg, tmat, f_w1, f_b1, scale, shift, g, c0, out);
}

// Round 2
// 367.697 us; speedup vs baseline: 1.4169x; 1.4169x over previous
//
#include <hip/hip_runtime.h>
#include <math.h>

constexpr int B_ = 64;
constexpr int N_ = 1000;
constexpr int D_ = 128;
constexpr int E_ = 20000;
constexpr int BN_TOT = B_ * N_;
constexpr float BN_EPS = 1e-5f;
constexpr float NEG_SLOPE = 0.2f;

__device__ __forceinline__ float leaky(float a) { return a >= 0.f ? a : NEG_SLOPE * a; }

// ---------------- small precompute kernels ----------------

__global__ void k_zero(int* base) {
    int i = threadIdx.x;
    for (int k = i; k < 2304; k += 256) base[k] = 0;
}

__global__ __launch_bounds__(64) void k_emb_scores(const float* __restrict__ emb,
                                                   const float* __restrict__ att_em_i,
                                                   const float* __restrict__ att_em_j,
                                                   float* __restrict__ eemi,
                                                   float* __restrict__ eemj) {
    int n = blockIdx.x;
    int lane = threadIdx.x;
    const float* er = emb + (size_t)n * D_;
    float e0 = er[lane], e1 = er[lane + 64];
    float si = e0 * att_em_i[lane] + e1 * att_em_i[lane + 64];
    float sj = e0 * att_em_j[lane] + e1 * att_em_j[lane + 64];
    for (int off = 32; off > 0; off >>= 1) {
        si += __shfl_down(si, off);
        sj += __shfl_down(sj, off);
    }
    if (lane == 0) { eemi[n] = si; eemj[n] = sj; }
}

__global__ void k_gvec(const float* __restrict__ f_w2, const float* __restrict__ f_b2,
                       const float* __restrict__ out_w, const float* __restrict__ out_b,
                       float* __restrict__ g, float* __restrict__ c0) {
    int j = threadIdx.x;  // 128
    float s = 0.f;
    for (int k = 0; k < D_; ++k) s += out_w[k] * f_w2[k * D_ + j];
    g[j] = s;
    if (j == 0) {
        float c = out_b[0];
        for (int k = 0; k < D_; ++k) c += out_w[k] * f_b2[k];
        *c0 = c;
    }
}

// ---------------- dual GEMM: x = data@lin_w.T ; t = data@v_w.T + v_b ----------------
// 256 threads: d = tid&127 (output channel for BOTH matrices), kh = tid>>7 (K half).
// Weights for K-half in registers (64+64). Activations broadcast from LDS as float4.
// FMA:LDS-read ratio = 8 FMA (16 cyc) per ds_read_b128 (12 cyc) -> FMA-bound.
__global__ __launch_bounds__(256) void k_dual_gemm(const float* __restrict__ data,
                                                   const float* __restrict__ lin_w,
                                                   const float* __restrict__ v_w,
                                                   const float* __restrict__ v_b,
                                                   float* __restrict__ x,
                                                   float* __restrict__ tmat) {
    const int tid = threadIdx.x;
    const int d = tid & 127;
    const int kh = tid >> 7;   // K half: [kh*64, kh*64+64)
    float w0[64], w1[64];
    {
        const float* l0 = lin_w + (size_t)d * D_ + kh * 64;
        const float* l1 = v_w + (size_t)d * D_ + kh * 64;
#pragma unroll
        for (int kk = 0; kk < 64; ++kk) { w0[kk] = l0[kk]; w1[kk] = l1[kk]; }
    }
    const float vb = v_b[d];
    __shared__ float sdata[8][D_];
    __shared__ float red[2][8][D_];   // kh=1 partials
    const int ntiles = BN_TOT / 8;
    for (int tile = blockIdx.x; tile < ntiles; tile += gridDim.x) {
        const int row0 = tile * 8;
        ((float4*)sdata)[tid] = ((const float4*)(data + (size_t)row0 * D_))[tid];
        __syncthreads();
        float acc0[8], acc1[8];
#pragma unroll
        for (int r = 0; r < 8; ++r) { acc0[r] = 0.f; acc1[r] = 0.f; }
#pragma unroll
        for (int k4 = 0; k4 < 16; ++k4) {
#pragma unroll
            for (int r = 0; r < 8; ++r) {
                float4 sd = *(const float4*)&sdata[r][kh * 64 + k4 * 4];
                acc0[r] += sd.x * w0[k4 * 4 + 0] + sd.y * w0[k4 * 4 + 1]
                         + sd.z * w0[k4 * 4 + 2] + sd.w * w0[k4 * 4 + 3];
                acc1[r] += sd.x * w1[k4 * 4 + 0] + sd.y * w1[k4 * 4 + 1]
                         + sd.z * w1[k4 * 4 + 2] + sd.w * w1[k4 * 4 + 3];
            }
        }
        if (kh == 1) {
#pragma unroll
            for (int r = 0; r < 8; ++r) { red[0][r][d] = acc0[r]; red[1][r][d] = acc1[r]; }
        }
        __syncthreads();
        if (kh == 0) {
#pragma unroll
            for (int r = 0; r < 8; ++r) {
                x[(size_t)(row0 + r) * D_ + d] = acc0[r] + red[0][r][d];
                tmat[(size_t)(row0 + r) * D_ + d] = acc1[r] + red[1][r][d] + vb;
            }
        }
        __syncthreads();
    }
}

// ---------------- node attention scores ----------------
__global__ __launch_bounds__(256) void k_scores(const float* __restrict__ x,
                                                const float* __restrict__ att_i,
                                                const float* __restrict__ att_j,
                                                const float* __restrict__ eemi,
                                                const float* __restrict__ eemj,
                                                float* __restrict__ ni, float* __restrict__ nj) {
    const int wid = threadIdx.x >> 6;
    const int lane = threadIdx.x & 63;
    const int row = blockIdx.x * 4 + wid;
    const float* xr = x + (size_t)row * D_;
    float x0 = xr[lane], x1 = xr[lane + 64];
    float si = x0 * att_i[lane] + x1 * att_i[lane + 64];
    float sj = x0 * att_j[lane] + x1 * att_j[lane + 64];
    for (int off = 32; off > 0; off >>= 1) {
        si += __shfl_down(si, off);
        sj += __shfl_down(sj, off);
    }
    if (lane == 0) {
        int n = row % N_;
        ni[row] = si + eemi[n];
        nj[row] = sj + eemj[n];
    }
}

// ---------------- CSR build ----------------
__global__ void k_count(const int* __restrict__ ei, int* __restrict__ offs) {
    int e = blockIdx.x * blockDim.x + threadIdx.x;
    if (e < E_) atomicAdd(&offs[ei[E_ + e] + 1], 1);
}

__global__ __launch_bounds__(1024) void k_scan(int* __restrict__ offs) {
    __shared__ int s[N_ + 1];
    int tid = threadIdx.x;
    if (tid <= N_) s[tid] = offs[tid];
    __syncthreads();
    for (int off = 1; off <= N_; off <<= 1) {
        int v = 0;
        if (tid <= N_) { v = s[tid]; if (tid >= off) v += s[tid - off]; }
        __syncthreads();
        if (tid <= N_) s[tid] = v;
        __syncthreads();
    }
    if (tid <= N_) offs[tid] = s[tid];
}

__global__ void k_scatter(const int* __restrict__ ei, const int* __restrict__ offs,
                          int* __restrict__ cursor, int* __restrict__ csr_src) {
    int e = blockIdx.x * blockDim.x + threadIdx.x;
    if (e < E_) {
        int dn = ei[E_ + e];
        int pos = offs[dn] + atomicAdd(&cursor[dn], 1);
        csr_src[pos] = ei[e];
    }
}

// ---------------- edge softmax: one WAVE per (b,i); transcendentals once ----------------
__global__ __launch_bounds__(256) void k_edge_w(const float* __restrict__ ni,
                                                const float* __restrict__ nj,
                                                const int* __restrict__ offs,
                                                const int* __restrict__ csr_src,
                                                float* __restrict__ exbuf,
                                                float* __restrict__ selfex,
                                                float* __restrict__ denomv) {
    const int wid = threadIdx.x >> 6;
    const int lane = threadIdx.x & 63;
    const int bid = blockIdx.x * 4 + wid;
    const int b = bid / N_;
    const int i = bid - b * N_;
    const int base = b * N_;
    const int e0 = offs[i], e1 = offs[i + 1];
    const float nii = ni[bid];
    const float aself = leaky(nii + nj[bid]);
    float amax = aself;
    for (int e = e0 + lane; e < e1; e += 64) {
        int s = csr_src[e];
        amax = fmaxf(amax, leaky(nii + nj[base + s]));
    }
    for (int off = 32; off > 0; off >>= 1) amax = fmaxf(amax, __shfl_xor(amax, off));
    float sum = 0.f;
    if (lane == 0) {
        float se = __expf(aself - amax);
        selfex[bid] = se;
        sum = se;
    }
    for (int e = e0 + lane; e < e1; e += 64) {
        int s = csr_src[e];
        float ex = __expf(leaky(nii + nj[base + s]) - amax);
        exbuf[(size_t)b * E_ + e] = ex;
        sum += ex;
    }
    for (int off = 32; off > 0; off >>= 1) sum += __shfl_xor(sum, off);
    if (lane == 0) denomv[bid] = sum;
}

// ---------------- SpMM gather-aggregate: 2 segments per block, XCD-swizzled ----------------
__global__ __launch_bounds__(256) void k_spmm(const float* __restrict__ x,
                                              const int* __restrict__ offs,
                                              const int* __restrict__ csr_src,
                                              const float* __restrict__ exbuf,
                                              const float* __restrict__ selfex,
                                              const float* __restrict__ denomv,
                                              const float* __restrict__ gnn_bias,
                                              float* __restrict__ agg) {
    constexpr int CAP = 256;
    __shared__ int s_lds[2][CAP];
    __shared__ float w_lds[2][CAP];
    // XCD swizzle: grid 32000 = 8 * 4000; XCD k gets contiguous 4000 blocks = 8 batches (4 MiB x-slice = its L2)
    const int swz = (blockIdx.x & 7) * 4000 + (blockIdx.x >> 3);
    const int half = threadIdx.x >> 7;
    const int d = threadIdx.x & 127;
    const int bid = swz * 2 + half;
    const int b = bid / N_;
    const int i = bid - b * N_;
    const int base = b * N_;
    const int e0 = offs[i];
    const int deg = offs[i + 1] - e0;
    const int stg = deg < CAP ? deg : CAP;
    for (int k = d; k < stg; k += 128) {
        s_lds[half][k] = csr_src[e0 + k];
        w_lds[half][k] = exbuf[(size_t)b * E_ + e0 + k];
    }
    __syncthreads();
    float acc = selfex[bid] * x[(size_t)bid * D_ + d];
    int k = 0;
    for (; k + 4 <= stg; k += 4) {
        int s0 = s_lds[half][k], s1 = s_lds[half][k + 1], s2 = s_lds[half][k + 2], s3 = s_lds[half][k + 3];
        float w0 = w_lds[half][k], w1 = w_lds[half][k + 1], w2 = w_lds[half][k + 2], w3 = w_lds[half][k + 3];
        float x0 = x[(size_t)(base + s0) * D_ + d];
        float x1 = x[(size_t)(base + s1) * D_ + d];
        float x2 = x[(size_t)(base + s2) * D_ + d];
        float x3 = x[(size_t)(base + s3) * D_ + d];
        acc += w0 * x0 + w1 * x1 + w2 * x2 + w3 * x3;
    }
    for (; k < stg; ++k)
        acc += w_lds[half][k] * x[(size_t)(base + s_lds[half][k]) * D_ + d];
    for (int e = e0 + CAP; e < e0 + deg; ++e) {  // overflow fallback (deg > CAP)
        int s = csr_src[e];
        acc += exbuf[(size_t)b * E_ + e] * x[(size_t)(base + s) * D_ + d];
    }
    agg[(size_t)bid * D_ + d] = acc / denomv[bid] + gnn_bias[d];
}

// ---------------- BatchNorm statistics ----------------
__global__ __launch_bounds__(128) void k_bn_stats(const float* __restrict__ agg,
                                                  float* __restrict__ bn_sum,
                                                  float* __restrict__ bn_sumsq) {
    const int d = threadIdx.x;
    const int rows_per = (BN_TOT + gridDim.x - 1) / gridDim.x;
    const int r0 = blockIdx.x * rows_per;
    const int r1 = min(r0 + rows_per, BN_TOT);
    float s = 0.f, sq = 0.f;
    for (int r = r0; r < r1; ++r) {
        float v = agg[(size_t)r * D_ + d];
        s += v;
        sq += v * v;
    }
    atomicAdd(&bn_sum[d], s);
    atomicAdd(&bn_sumsq[d], sq);
}

__global__ void k_bn_fin(const float* __restrict__ bn_sum, const float* __restrict__ bn_sumsq,
                         const float* __restrict__ gamma, const float* __restrict__ beta,
                         float* __restrict__ scale, float* __restrict__ shift) {
    int d = threadIdx.x;
    float mu = bn_sum[d] * (1.f / BN_TOT);
    float var = bn_sumsq[d] * (1.f / BN_TOT) - mu * mu;
    float sc = gamma[d] * rsqrtf(var + BN_EPS);
    scale[d] = sc;
    shift[d] = beta[d] - mu * sc;
}

// ---------------- fusion MLP (folded output layer) ----------------
// out[r] = g . relu( W1 @ [bn_relu(agg[r]) | t[r]] + b1 ) + c0
// 256 threads: c = tid&63 -> channels {c, c+64}; kq = tid>>6 -> K quarter of 256.
// Weights 2x64 in registers; comb broadcast as float4; partial-K reduce via LDS.
__global__ __launch_bounds__(256) void k_fusion(const float* __restrict__ agg,
                                                const float* __restrict__ tmat,
                                                const float* __restrict__ f_w1,
                                                const float* __restrict__ f_b1,
                                                const float* __restrict__ scale,
                                                const float* __restrict__ shift,
                                                const float* __restrict__ g,
                                                const float* __restrict__ c0p,
                                                float* __restrict__ out) {
    const int tid = threadIdx.x;
    const int c = tid & 63;
    const int kq = tid >> 6;   // K quarter: [kq*64, kq*64+64) of 256
    float wA[64], wB[64];
    {
        const float* ra = f_w1 + (size_t)c * (2 * D_) + kq * 64;
        const float* rb = f_w1 + (size_t)(c + 64) * (2 * D_) + kq * 64;
#pragma unroll
        for (int kk = 0; kk < 64; ++kk) { wA[kk] = ra[kk]; wB[kk] = rb[kk]; }
    }
    __shared__ float comb[8][2 * D_];
    __shared__ float part[4][8][D_];
    const float c0 = *c0p;
    const int ntiles = BN_TOT / 8;
    for (int tile = blockIdx.x; tile < ntiles; tile += gridDim.x) {
        const int row0 = tile * 8;
        // stage 8 rows of [bn_relu(agg) | t] as float4
#pragma unroll
        for (int q = 0; q < 2; ++q) {
            int idx = tid + q * 256;       // float4 index in [0,512)
            int r = idx >> 6;
            int c4 = idx & 63;             // float4 col
            float4 v;
            if (c4 < 32) {
                float4 a = *(const float4*)&agg[(size_t)(row0 + r) * D_ + c4 * 4];
                float4 sc = *(const float4*)&scale[c4 * 4];
                float4 sh = *(const float4*)&shift[c4 * 4];
                v.x = fmaxf(sc.x * a.x + sh.x, 0.f);
                v.y = fmaxf(sc.y * a.y + sh.y, 0.f);
                v.z = fmaxf(sc.z * a.z + sh.z, 0.f);
                v.w = fmaxf(sc.w * a.w + sh.w, 0.f);
            } else {
                v = *(const float4*)&tmat[(size_t)(row0 + r) * D_ + (c4 - 32) * 4];
            }
            *(float4*)&comb[r][c4 * 4] = v;
        }
        __syncthreads();
        float accA[8], accB[8];
#pragma unroll
        for (int r = 0; r < 8; ++r) { accA[r] = 0.f; accB[r] = 0.f; }
#pragma unroll
        for (int k4 = 0; k4 < 16; ++k4) {
#pragma unroll
            for (int r = 0; r < 8; ++r) {
                float4 sd = *(const float4*)&comb[r][kq * 64 + k4 * 4];
                accA[r] += sd.x * wA[k4 * 4 + 0] + sd.y * wA[k4 * 4 + 1]
                         + sd.z * wA[k4 * 4 + 2] + sd.w * wA[k4 * 4 + 3];
                accB[r] += sd.x * wB[k4 * 4 + 0] + sd.y * wB[k4 * 4 + 1]
                         + sd.z * wB[k4 * 4 + 2] + sd.w * wB[k4 * 4 + 3];
            }
        }
#pragma unroll
        for (int r = 0; r < 8; ++r) {
            part[kq][r][c] = accA[r];
            part[kq][r][c + 64] = accB[r];
        }
        __syncthreads();
        {
            const int r = tid >> 5;          // row 0..7
            const int l32 = tid & 31;
            const int ch = l32 * 4;          // 4 channels per thread
            float4 h = *(const float4*)&part[0][r][ch];
            float4 p1 = *(const float4*)&part[1][r][ch];
            float4 p2 = *(const float4*)&part[2][r][ch];
            float4 p3 = *(const float4*)&part[3][r][ch];
            float4 bb = *(const float4*)&f_b1[ch];
            float4 gg = *(const float4*)&g[ch];
            h.x = fmaxf(h.x + p1.x + p2.x + p3.x + bb.x, 0.f);
            h.y = fmaxf(h.y + p1.y + p2.y + p3.y + bb.y, 0.f);
            h.z = fmaxf(h.z + p1.z + p2.z + p3.z + bb.z, 0.f);
            h.w = fmaxf(h.w + p1.w + p2.w + p3.w + bb.w, 0.f);
            float p = h.x * gg.x + h.y * gg.y + h.z * gg.z + h.w * gg.w;
            for (int off = 16; off > 0; off >>= 1) p += __shfl_xor(p, off, 32);
            if (l32 == 0) out[row0 + r] = p + c0;
        }
        __syncthreads();
    }
}

// ---------------- launch ----------------
extern "C" void kernel_launch(void* const* d_in, const int* in_sizes, int n_in,
                              void* d_out, int out_size, void* d_ws, size_t ws_size,
                              hipStream_t stream) {
    const float* data     = (const float*)d_in[0];
    const int*   ei       = (const int*)d_in[1];
    const float* emb      = (const float*)d_in[2];
    const float* lin_w    = (const float*)d_in[3];
    const float* att_i    = (const float*)d_in[4];
    const float* att_j    = (const float*)d_in[5];
    const float* att_em_i = (const float*)d_in[6];
    const float* att_em_j = (const float*)d_in[7];
    const float* gnn_bias = (const float*)d_in[8];
    const float* bn_gamma = (const float*)d_in[9];
    const float* bn_beta  = (const float*)d_in[10];
    // q_w,q_b,k_w,k_b,temperature dead (W=1 -> softmax over single element -> attn==1)
    const float* v_w      = (const float*)d_in[15];
    const float* v_b      = (const float*)d_in[16];
    const float* f_w1     = (const float*)d_in[18];
    const float* f_b1     = (const float*)d_in[19];
    const float* f_w2     = (const float*)d_in[20];
    const float* f_b2     = (const float*)d_in[21];
    const float* out_w    = (const float*)d_in[22];
    const float* out_b    = (const float*)d_in[23];
    float* out = (float*)d_out;

    float* ws = (float*)d_ws;
    float* x      = ws;                                 // BN*D
    float* tmat   = x + (size_t)BN_TOT * D_;            // BN*D
    float* agg    = tmat + (size_t)BN_TOT * D_;         // BN*D
    float* ni     = agg + (size_t)BN_TOT * D_;          // BN
    float* nj     = ni + BN_TOT;                        // BN
    float* eemi   = nj + BN_TOT;                        // N
    float* eemj   = eemi + N_;                          // N
    float* g      = eemj + N_;                          // D
    float* c0     = g + D_;                             // 1 (pad 8)
    float* scale  = c0 + 8;                             // D
    float* shift  = scale + D_;                         // D
    int* offs     = (int*)(shift + D_);                 // 1024 [zeroed]
    int* cursor   = offs + 1024;                        // 1024 [zeroed]
    float* bn_sum = (float*)(cursor + 1024);            // 128  [zeroed]
    float* bn_sq  = bn_sum + D_;                        // 128  [zeroed]
    int* csr_src  = (int*)(bn_sq + D_);                 // E
    float* exbuf  = (float*)(csr_src + E_);             // B*E
    float* selfex = exbuf + (size_t)B_ * E_;            // BN
    float* denomv = selfex + BN_TOT;                    // BN

    k_zero<<<1, 256, 0, stream>>>(offs);
    k_emb_scores<<<N_, 64, 0, stream>>>(emb, att_em_i, att_em_j, eemi, eemj);
    k_gvec<<<1, 128, 0, stream>>>(f_w2, f_b2, out_w, out_b, g, c0);
    k_dual_gemm<<<1024, 256, 0, stream>>>(data, lin_w, v_w, v_b, x, tmat);
    k_scores<<<BN_TOT / 4, 256, 0, stream>>>(x, att_i, att_j, eemi, eemj, ni, nj);
    k_count<<<(E_ + 255) / 256, 256, 0, stream>>>(ei, offs);
    k_scan<<<1, 1024, 0, stream>>>(offs);
    k_scatter<<<(E_ + 255) / 256, 256, 0, stream>>>(ei, offs, cursor, csr_src);
    k_edge_w<<<BN_TOT / 4, 256, 0, stream>>>(ni, nj, offs, csr_src, exbuf, selfex, denomv);
    k_spmm<<<BN_TOT / 2, 256, 0, stream>>>(x, offs, csr_src, exbuf, selfex, denomv, gnn_bias, agg);
    k_bn_stats<<<256, 128, 0, stream>>>(agg, bn_sum, bn_sq);
    k_bn_fin<<<1, 128, 0, stream>>>(bn_sum, bn_sq, bn_gamma, bn_beta, scale, shift);
    k_fusion<<<1024, 256, 0, stream>>>(agg, tmat, f_w1, f_b1, scale, shift, g, c0, out);
}

// Round 3
// 241.694 us; speedup vs baseline: 2.1556x; 1.5213x over previous
//
#include <hip/hip_runtime.h>
#include <math.h>

constexpr int B_ = 64;
constexpr int N_ = 1000;
constexpr int D_ = 128;
constexpr int E_ = 20000;
constexpr int BN_TOT = B_ * N_;
constexpr float BN_EPS = 1e-5f;
constexpr float NEG_SLOPE = 0.2f;

typedef __attribute__((ext_vector_type(8))) __bf16 bf16x8;
typedef __attribute__((ext_vector_type(4))) float f32x4;

__device__ __forceinline__ float leaky(float a) { return a >= 0.f ? a : NEG_SLOPE * a; }

__device__ __forceinline__ void split8(const float* v, bf16x8& h, bf16x8& l) {
#pragma unroll
    for (int j = 0; j < 8; ++j) {
        __bf16 hh = (__bf16)v[j];
        h[j] = hh;
        l[j] = (__bf16)(v[j] - (float)hh);
    }
}

// ---------------- small precompute kernels ----------------

__global__ void k_zero(int* base) {
    int i = threadIdx.x;
    for (int k = i; k < 2304; k += 256) base[k] = 0;
}

__global__ __launch_bounds__(64) void k_emb_scores(const float* __restrict__ emb,
                                                   const float* __restrict__ att_em_i,
                                                   const float* __restrict__ att_em_j,
                                                   float* __restrict__ eemi,
                                                   float* __restrict__ eemj) {
    int n = blockIdx.x;
    int lane = threadIdx.x;
    const float* er = emb + (size_t)n * D_;
    float e0 = er[lane], e1 = er[lane + 64];
    float si = e0 * att_em_i[lane] + e1 * att_em_i[lane + 64];
    float sj = e0 * att_em_j[lane] + e1 * att_em_j[lane + 64];
    for (int off = 32; off > 0; off >>= 1) {
        si += __shfl_down(si, off);
        sj += __shfl_down(sj, off);
    }
    if (lane == 0) { eemi[n] = si; eemj[n] = sj; }
}

__global__ void k_gvec(const float* __restrict__ f_w2, const float* __restrict__ f_b2,
                       const float* __restrict__ out_w, const float* __restrict__ out_b,
                       float* __restrict__ g, float* __restrict__ c0) {
    int j = threadIdx.x;  // 128
    float s = 0.f;
    for (int k = 0; k < D_; ++k) s += out_w[k] * f_w2[k * D_ + j];
    g[j] = s;
    if (j == 0) {
        float c = out_b[0];
        for (int k = 0; k < D_; ++k) c += out_w[k] * f_b2[k];
        *c0 = c;
    }
}

// split weights into bf16 hi/lo: wcat[256][128] = [lin_w ; v_w], f1[128][256] = f_w1
__global__ void k_wprep(const float* __restrict__ lin_w, const float* __restrict__ v_w,
                        const float* __restrict__ f_w1,
                        __bf16* __restrict__ wcat_h, __bf16* __restrict__ wcat_l,
                        __bf16* __restrict__ f1_h, __bf16* __restrict__ f1_l) {
    int i = blockIdx.x * 256 + threadIdx.x;  // 65536 total
    if (i < 32768) {
        float v = (i < 16384) ? lin_w[i] : v_w[i - 16384];
        __bf16 h = (__bf16)v;
        wcat_h[i] = h;
        wcat_l[i] = (__bf16)(v - (float)h);
    } else {
        int j = i - 32768;
        float v = f_w1[j];
        __bf16 h = (__bf16)v;
        f1_h[j] = h;
        f1_l[j] = (__bf16)(v - (float)h);
    }
}

// ---------------- MFMA dual GEMM: [x | t] = data @ [lin_w ; v_w]^T (+v_b on t half) ----------
// block 512 thr (8 waves). Wave w owns cols [w*32, w*32+32) (2 n-tiles). Chunk = 32 rows.
// data chunk staged in LDS as split bf16 hi/lo with XOR swizzle; 3-MFMA split product.
__global__ __launch_bounds__(512) void k_mfma_dual(const float* __restrict__ data,
                                                   const __bf16* __restrict__ wcat_h,
                                                   const __bf16* __restrict__ wcat_l,
                                                   const float* __restrict__ v_b,
                                                   float* __restrict__ x,
                                                   float* __restrict__ tmat) {
    const int tid = threadIdx.x;
    const int w = tid >> 6;
    const int l = tid & 63;
    // B fragments (persist across chunks): nt in {0,1}, kk in {0..3}
    bf16x8 Bh[2][4], Bl[2][4];
#pragma unroll
    for (int nt = 0; nt < 2; ++nt) {
        const int n = w * 32 + nt * 16 + (l & 15);
#pragma unroll
        for (int kk = 0; kk < 4; ++kk) {
            const int k = kk * 32 + (l >> 4) * 8;
            Bh[nt][kk] = *(const bf16x8*)&wcat_h[n * D_ + k];
            Bl[nt][kk] = *(const bf16x8*)&wcat_l[n * D_ + k];
        }
    }
    float vb[2] = {0.f, 0.f};
    if (w >= 4) {
#pragma unroll
        for (int nt = 0; nt < 2; ++nt) vb[nt] = v_b[w * 32 + nt * 16 + (l & 15) - 128];
    }
    __shared__ __align__(16) __bf16 dh[32 * D_];
    __shared__ __align__(16) __bf16 dl[32 * D_];
    const int srow = tid >> 4;            // staging row 0..31
    const int skq = (tid & 15) * 8;       // staging k offset
    const int sidx = srow * D_ + (skq ^ ((srow & 7) * 8));
    const int nchunks = BN_TOT / 32;
    for (int ch = blockIdx.x; ch < nchunks; ch += gridDim.x) {
        const int row0 = ch * 32;
        {   // stage 32x128 fp32 -> bf16 hi/lo (swizzled)
            const float* src = data + (size_t)(row0 + srow) * D_ + skq;
            float v[8];
            float4 p0 = *(const float4*)src;
            float4 p1 = *(const float4*)(src + 4);
            v[0] = p0.x; v[1] = p0.y; v[2] = p0.z; v[3] = p0.w;
            v[4] = p1.x; v[5] = p1.y; v[6] = p1.z; v[7] = p1.w;
            bf16x8 hv, lv;
            split8(v, hv, lv);
            *(bf16x8*)&dh[sidx] = hv;
            *(bf16x8*)&dl[sidx] = lv;
        }
        __syncthreads();
        f32x4 acc[2][2];
#pragma unroll
        for (int mt = 0; mt < 2; ++mt)
#pragma unroll
            for (int nt = 0; nt < 2; ++nt) acc[mt][nt] = (f32x4){0.f, 0.f, 0.f, 0.f};
#pragma unroll
        for (int mt = 0; mt < 2; ++mt) {
#pragma unroll
            for (int kk = 0; kk < 4; ++kk) {
                const int ai = (mt * 16 + (l & 15)) * D_ + ((kk * 32 + (l >> 4) * 8) ^ ((l & 7) * 8));
                bf16x8 ah = *(const bf16x8*)&dh[ai];
                bf16x8 al = *(const bf16x8*)&dl[ai];
#pragma unroll
                for (int nt = 0; nt < 2; ++nt) {
                    acc[mt][nt] = __builtin_amdgcn_mfma_f32_16x16x32_bf16(ah, Bh[nt][kk], acc[mt][nt], 0, 0, 0);
                    acc[mt][nt] = __builtin_amdgcn_mfma_f32_16x16x32_bf16(ah, Bl[nt][kk], acc[mt][nt], 0, 0, 0);
                    acc[mt][nt] = __builtin_amdgcn_mfma_f32_16x16x32_bf16(al, Bh[nt][kk], acc[mt][nt], 0, 0, 0);
                }
            }
        }
        // epilogue: C/D layout col=lane&15, row=(lane>>4)*4+reg
#pragma unroll
        for (int mt = 0; mt < 2; ++mt) {
#pragma unroll
            for (int nt = 0; nt < 2; ++nt) {
                const int col = w * 32 + nt * 16 + (l & 15);
                const int rg = row0 + mt * 16 + (l >> 4) * 4;
                if (w < 4) {
#pragma unroll
                    for (int r = 0; r < 4; ++r)
                        x[(size_t)(rg + r) * D_ + col] = acc[mt][nt][r];
                } else {
                    const int c2 = col - 128;
#pragma unroll
                    for (int r = 0; r < 4; ++r)
                        tmat[(size_t)(rg + r) * D_ + c2] = acc[mt][nt][r] + vb[nt];
                }
            }
        }
        __syncthreads();
    }
}

// ---------------- node attention scores ----------------
__global__ __launch_bounds__(256) void k_scores(const float* __restrict__ x,
                                                const float* __restrict__ att_i,
                                                const float* __restrict__ att_j,
                                                const float* __restrict__ eemi,
                                                const float* __restrict__ eemj,
                                                float* __restrict__ ni, float* __restrict__ nj) {
    const int wid = threadIdx.x >> 6;
    const int lane = threadIdx.x & 63;
    const int row = blockIdx.x * 4 + wid;
    const float* xr = x + (size_t)row * D_;
    float x0 = xr[lane], x1 = xr[lane + 64];
    float si = x0 * att_i[lane] + x1 * att_i[lane + 64];
    float sj = x0 * att_j[lane] + x1 * att_j[lane + 64];
    for (int off = 32; off > 0; off >>= 1) {
        si += __shfl_down(si, off);
        sj += __shfl_down(sj, off);
    }
    if (lane == 0) {
        int n = row % N_;
        ni[row] = si + eemi[n];
        nj[row] = sj + eemj[n];
    }
}

// ---------------- CSR build ----------------
__global__ void k_count(const int* __restrict__ ei, int* __restrict__ offs) {
    int e = blockIdx.x * blockDim.x + threadIdx.x;
    if (e < E_) atomicAdd(&offs[ei[E_ + e] + 1], 1);
}

__global__ __launch_bounds__(1024) void k_scan(int* __restrict__ offs) {
    __shared__ int s[N_ + 1];
    int tid = threadIdx.x;
    if (tid <= N_) s[tid] = offs[tid];
    __syncthreads();
    for (int off = 1; off <= N_; off <<= 1) {
        int v = 0;
        if (tid <= N_) { v = s[tid]; if (tid >= off) v += s[tid - off]; }
        __syncthreads();
        if (tid <= N_) s[tid] = v;
        __syncthreads();
    }
    if (tid <= N_) offs[tid] = s[tid];
}

__global__ void k_scatter(const int* __restrict__ ei, const int* __restrict__ offs,
                          int* __restrict__ cursor, int* __restrict__ csr_src) {
    int e = blockIdx.x * blockDim.x + threadIdx.x;
    if (e < E_) {
        int dn = ei[E_ + e];
        int pos = offs[dn] + atomicAdd(&cursor[dn], 1);
        csr_src[pos] = ei[e];
    }
}

// ---------------- edge softmax: one WAVE per (b,i) ----------------
__global__ __launch_bounds__(256) void k_edge_w(const float* __restrict__ ni,
                                                const float* __restrict__ nj,
                                                const int* __restrict__ offs,
                                                const int* __restrict__ csr_src,
                                                float* __restrict__ exbuf,
                                                float* __restrict__ selfex,
                                                float* __restrict__ denomv) {
    const int wid = threadIdx.x >> 6;
    const int lane = threadIdx.x & 63;
    const int bid = blockIdx.x * 4 + wid;
    const int b = bid / N_;
    const int i = bid - b * N_;
    const int base = b * N_;
    const int e0 = offs[i], e1 = offs[i + 1];
    const float nii = ni[bid];
    const float aself = leaky(nii + nj[bid]);
    float amax = aself;
    for (int e = e0 + lane; e < e1; e += 64) {
        int s = csr_src[e];
        amax = fmaxf(amax, leaky(nii + nj[base + s]));
    }
    for (int off = 32; off > 0; off >>= 1) amax = fmaxf(amax, __shfl_xor(amax, off));
    float sum = 0.f;
    if (lane == 0) {
        float se = __expf(aself - amax);
        selfex[bid] = se;
        sum = se;
    }
    for (int e = e0 + lane; e < e1; e += 64) {
        int s = csr_src[e];
        float ex = __expf(leaky(nii + nj[base + s]) - amax);
        exbuf[(size_t)b * E_ + e] = ex;
        sum += ex;
    }
    for (int off = 32; off > 0; off >>= 1) sum += __shfl_xor(sum, off);
    if (lane == 0) denomv[bid] = sum;
}

// ---------------- SpMM gather-aggregate: 2 segments per block, XCD-swizzled ----------------
__global__ __launch_bounds__(256) void k_spmm(const float* __restrict__ x,
                                              const int* __restrict__ offs,
                                              const int* __restrict__ csr_src,
                                              const float* __restrict__ exbuf,
                                              const float* __restrict__ selfex,
                                              const float* __restrict__ denomv,
                                              const float* __restrict__ gnn_bias,
                                              float* __restrict__ agg) {
    constexpr int CAP = 256;
    __shared__ int s_lds[2][CAP];
    __shared__ float w_lds[2][CAP];
    const int swz = (blockIdx.x & 7) * 4000 + (blockIdx.x >> 3);
    const int half = threadIdx.x >> 7;
    const int d = threadIdx.x & 127;
    const int bid = swz * 2 + half;
    const int b = bid / N_;
    const int i = bid - b * N_;
    const int base = b * N_;
    const int e0 = offs[i];
    const int deg = offs[i + 1] - e0;
    const int stg = deg < CAP ? deg : CAP;
    for (int k = d; k < stg; k += 128) {
        s_lds[half][k] = csr_src[e0 + k];
        w_lds[half][k] = exbuf[(size_t)b * E_ + e0 + k];
    }
    __syncthreads();
    float acc = selfex[bid] * x[(size_t)bid * D_ + d];
    int k = 0;
    for (; k + 4 <= stg; k += 4) {
        int s0 = s_lds[half][k], s1 = s_lds[half][k + 1], s2 = s_lds[half][k + 2], s3 = s_lds[half][k + 3];
        float w0 = w_lds[half][k], w1 = w_lds[half][k + 1], w2 = w_lds[half][k + 2], w3 = w_lds[half][k + 3];
        float x0 = x[(size_t)(base + s0) * D_ + d];
        float x1 = x[(size_t)(base + s1) * D_ + d];
        float x2 = x[(size_t)(base + s2) * D_ + d];
        float x3 = x[(size_t)(base + s3) * D_ + d];
        acc += w0 * x0 + w1 * x1 + w2 * x2 + w3 * x3;
    }
    for (; k < stg; ++k)
        acc += w_lds[half][k] * x[(size_t)(base + s_lds[half][k]) * D_ + d];
    for (int e = e0 + CAP; e < e0 + deg; ++e) {
        int s = csr_src[e];
        acc += exbuf[(size_t)b * E_ + e] * x[(size_t)(base + s) * D_ + d];
    }
    agg[(size_t)bid * D_ + d] = acc / denomv[bid] + gnn_bias[d];
}

// ---------------- BatchNorm statistics ----------------
__global__ __launch_bounds__(128) void k_bn_stats(const float* __restrict__ agg,
                                                  float* __restrict__ bn_sum,
                                                  float* __restrict__ bn_sumsq) {
    const int d = threadIdx.x;
    const int rows_per = (BN_TOT + gridDim.x - 1) / gridDim.x;
    const int r0 = blockIdx.x * rows_per;
    const int r1 = min(r0 + rows_per, BN_TOT);
    float s = 0.f, sq = 0.f;
    for (int r = r0; r < r1; ++r) {
        float v = agg[(size_t)r * D_ + d];
        s += v;
        sq += v * v;
    }
    atomicAdd(&bn_sum[d], s);
    atomicAdd(&bn_sumsq[d], sq);
}

__global__ void k_bn_fin(const float* __restrict__ bn_sum, const float* __restrict__ bn_sumsq,
                         const float* __restrict__ gamma, const float* __restrict__ beta,
                         float* __restrict__ scale, float* __restrict__ shift) {
    int d = threadIdx.x;
    float mu = bn_sum[d] * (1.f / BN_TOT);
    float var = bn_sumsq[d] * (1.f / BN_TOT) - mu * mu;
    float sc = gamma[d] * rsqrtf(var + BN_EPS);
    scale[d] = sc;
    shift[d] = beta[d] - mu * sc;
}

// ---------------- MFMA fusion: out[r] = g·relu(f_w1 @ [bnrelu(agg[r])|t[r]] + b1) + c0 ----
// block 512 thr (8 waves). Wave w owns output cols [w*16, w*16+16). Chunk = 32 rows, K=256.
__global__ __launch_bounds__(512) void k_mfma_fusion(const float* __restrict__ agg,
                                                     const float* __restrict__ tmat,
                                                     const __bf16* __restrict__ f1_h,
                                                     const __bf16* __restrict__ f1_l,
                                                     const float* __restrict__ f_b1,
                                                     const float* __restrict__ scale,
                                                     const float* __restrict__ shift,
                                                     const float* __restrict__ g,
                                                     const float* __restrict__ c0p,
                                                     float* __restrict__ out) {
    const int tid = threadIdx.x;
    const int w = tid >> 6;
    const int l = tid & 63;
    const float c0v = *c0p;
    // B fragments: kk 0..7 (K=256)
    bf16x8 Fh[8], Fl[8];
    const int ncol = w * 16 + (l & 15);
#pragma unroll
    for (int kk = 0; kk < 8; ++kk) {
        const int k = kk * 32 + (l >> 4) * 8;
        Fh[kk] = *(const bf16x8*)&f1_h[ncol * 256 + k];
        Fl[kk] = *(const bf16x8*)&f1_l[ncol * 256 + k];
    }
    const float b1c = f_b1[ncol];
    const float gc = g[ncol];
    __shared__ __align__(16) __bf16 ch_[32 * 256];
    __shared__ __align__(16) __bf16 cl_[32 * 256];
    __shared__ float part[8][32];
    // staging role
    const int srow = tid >> 4;
    const int scb = (tid & 15) * 16;          // 16 cols of comb
    const bool isagg = scb < 128;
    float4 sc4[4], sh4[4];
    if (isagg) {
#pragma unroll
        for (int q = 0; q < 4; ++q) {
            sc4[q] = *(const float4*)&scale[scb + q * 4];
            sh4[q] = *(const float4*)&shift[scb + q * 4];
        }
    }
    const int nchunks = BN_TOT / 32;
    for (int chk = blockIdx.x; chk < nchunks; chk += gridDim.x) {
        const int row0 = chk * 32;
        {   // stage comb = [bnrelu(agg) | t] as split bf16 (swizzled)
            const float* srcp = isagg ? (agg + (size_t)(row0 + srow) * D_ + scb)
                                      : (tmat + (size_t)(row0 + srow) * D_ + (scb - 128));
            float v[16];
#pragma unroll
            for (int q = 0; q < 4; ++q) {
                float4 p = *(const float4*)(srcp + q * 4);
                if (isagg) {
                    p.x = fmaxf(p.x * sc4[q].x + sh4[q].x, 0.f);
                    p.y = fmaxf(p.y * sc4[q].y + sh4[q].y, 0.f);
                    p.z = fmaxf(p.z * sc4[q].z + sh4[q].z, 0.f);
                    p.w = fmaxf(p.w * sc4[q].w + sh4[q].w, 0.f);
                }
                v[q * 4 + 0] = p.x; v[q * 4 + 1] = p.y; v[q * 4 + 2] = p.z; v[q * 4 + 3] = p.w;
            }
#pragma unroll
            for (int hh = 0; hh < 2; ++hh) {
                bf16x8 hv, lv;
                split8(v + hh * 8, hv, lv);
                const int c = scb + hh * 8;
                const int idx = srow * 256 + (c ^ ((srow & 7) * 8));
                *(bf16x8*)&ch_[idx] = hv;
                *(bf16x8*)&cl_[idx] = lv;
            }
        }
        __syncthreads();
#pragma unroll
        for (int mt = 0; mt < 2; ++mt) {
            f32x4 acc = (f32x4){0.f, 0.f, 0.f, 0.f};
#pragma unroll
            for (int kk = 0; kk < 8; ++kk) {
                const int ai = (mt * 16 + (l & 15)) * 256 + ((kk * 32 + (l >> 4) * 8) ^ ((l & 7) * 8));
                bf16x8 ah = *(const bf16x8*)&ch_[ai];
                bf16x8 al = *(const bf16x8*)&cl_[ai];
                acc = __builtin_amdgcn_mfma_f32_16x16x32_bf16(ah, Fh[kk], acc, 0, 0, 0);
                acc = __builtin_amdgcn_mfma_f32_16x16x32_bf16(ah, Fl[kk], acc, 0, 0, 0);
                acc = __builtin_amdgcn_mfma_f32_16x16x32_bf16(al, Fh[kk], acc, 0, 0, 0);
            }
            float p[4];
#pragma unroll
            for (int r = 0; r < 4; ++r) p[r] = fmaxf(acc[r] + b1c, 0.f) * gc;
#pragma unroll
            for (int r = 0; r < 4; ++r) {
                p[r] += __shfl_xor(p[r], 1);
                p[r] += __shfl_xor(p[r], 2);
                p[r] += __shfl_xor(p[r], 4);
                p[r] += __shfl_xor(p[r], 8);
            }
            if ((l & 15) == 0) {
#pragma unroll
                for (int r = 0; r < 4; ++r) part[w][mt * 16 + (l >> 4) * 4 + r] = p[r];
            }
        }
        __syncthreads();
        if (tid < 32) {
            float s = c0v;
#pragma unroll
            for (int ww = 0; ww < 8; ++ww) s += part[ww][tid];
            out[row0 + tid] = s;
        }
        __syncthreads();
    }
}

// ---------------- launch ----------------
extern "C" void kernel_launch(void* const* d_in, const int* in_sizes, int n_in,
                              void* d_out, int out_size, void* d_ws, size_t ws_size,
                              hipStream_t stream) {
    const float* data     = (const float*)d_in[0];
    const int*   ei       = (const int*)d_in[1];
    const float* emb      = (const float*)d_in[2];
    const float* lin_w    = (const float*)d_in[3];
    const float* att_i    = (const float*)d_in[4];
    const float* att_j    = (const float*)d_in[5];
    const float* att_em_i = (const float*)d_in[6];
    const float* att_em_j = (const float*)d_in[7];
    const float* gnn_bias = (const float*)d_in[8];
    const float* bn_gamma = (const float*)d_in[9];
    const float* bn_beta  = (const float*)d_in[10];
    // q_w,q_b,k_w,k_b,temperature dead (W=1 -> softmax over single element -> attn==1)
    const float* v_w      = (const float*)d_in[15];
    const float* v_b      = (const float*)d_in[16];
    const float* f_w1     = (const float*)d_in[18];
    const float* f_b1     = (const float*)d_in[19];
    const float* f_w2     = (const float*)d_in[20];
    const float* f_b2     = (const float*)d_in[21];
    const float* out_w    = (const float*)d_in[22];
    const float* out_b    = (const float*)d_in[23];
    float* out = (float*)d_out;

    float* ws = (float*)d_ws;
    float* x      = ws;                                 // BN*D
    float* tmat   = x + (size_t)BN_TOT * D_;            // BN*D
    float* agg    = tmat + (size_t)BN_TOT * D_;         // BN*D
    float* ni     = agg + (size_t)BN_TOT * D_;          // BN
    float* nj     = ni + BN_TOT;                        // BN
    float* eemi   = nj + BN_TOT;                        // N
    float* eemj   = eemi + N_;                          // N
    float* g      = eemj + N_;                          // D
    float* c0     = g + D_;                             // 1 (pad 8)
    float* scale  = c0 + 8;                             // D
    float* shift  = scale + D_;                         // D
    int* offs     = (int*)(shift + D_);                 // 1024 [zeroed]
    int* cursor   = offs + 1024;                        // 1024 [zeroed]
    float* bn_sum = (float*)(cursor + 1024);            // 128  [zeroed]
    float* bn_sq  = bn_sum + D_;                        // 128  [zeroed]
    int* csr_src  = (int*)(bn_sq + D_);                 // E
    float* exbuf  = (float*)(csr_src + E_);             // B*E
    float* selfex = exbuf + (size_t)B_ * E_;            // BN
    float* denomv = selfex + BN_TOT;                    // BN
    __bf16* wcat_h = (__bf16*)(denomv + BN_TOT);        // 256*128
    __bf16* wcat_l = wcat_h + 256 * 128;                // 256*128
    __bf16* f1_h   = wcat_l + 256 * 128;                // 128*256
    __bf16* f1_l   = f1_h + 128 * 256;                  // 128*256

    k_zero<<<1, 256, 0, stream>>>(offs);
    k_emb_scores<<<N_, 64, 0, stream>>>(emb, att_em_i, att_em_j, eemi, eemj);
    k_gvec<<<1, 128, 0, stream>>>(f_w2, f_b2, out_w, out_b, g, c0);
    k_wprep<<<256, 256, 0, stream>>>(lin_w, v_w, f_w1, wcat_h, wcat_l, f1_h, f1_l);
    k_mfma_dual<<<512, 512, 0, stream>>>(data, wcat_h, wcat_l, v_b, x, tmat);
    k_scores<<<BN_TOT / 4, 256, 0, stream>>>(x, att_i, att_j, eemi, eemj, ni, nj);
    k_count<<<(E_ + 255) / 256, 256, 0, stream>>>(ei, offs);
    k_scan<<<1, 1024, 0, stream>>>(offs);
    k_scatter<<<(E_ + 255) / 256, 256, 0, stream>>>(ei, offs, cursor, csr_src);
    k_edge_w<<<BN_TOT / 4, 256, 0, stream>>>(ni, nj, offs, csr_src, exbuf, selfex, denomv);
    k_spmm<<<BN_TOT / 2, 256, 0, stream>>>(x, offs, csr_src, exbuf, selfex, denomv, gnn_bias, agg);
    k_bn_stats<<<256, 128, 0, stream>>>(agg, bn_sum, bn_sq);
    k_bn_fin<<<1, 128, 0, stream>>>(bn_sum, bn_sq, bn_gamma, bn_beta, scale, shift);
    k_mfma_fusion<<<512, 512, 0, stream>>>(agg, tmat, f1_h, f1_l, f_b1, scale, shift, g, c0, out);
}

// Round 4
// 219.754 us; speedup vs baseline: 2.3708x; 1.0998x over previous
//
#include <hip/hip_runtime.h>
#include <math.h>

constexpr int B_ = 64;
constexpr int N_ = 1000;
constexpr int D_ = 128;
constexpr int E_ = 20000;
constexpr int BN_TOT = B_ * N_;
constexpr float BN_EPS = 1e-5f;
constexpr float NEG_SLOPE = 0.2f;

typedef __attribute__((ext_vector_type(8))) __bf16 bf16x8;
typedef __attribute__((ext_vector_type(4))) float f32x4;

__device__ __forceinline__ float leaky(float a) { return a >= 0.f ? a : NEG_SLOPE * a; }

__device__ __forceinline__ void split8(const float* v, bf16x8& h, bf16x8& l) {
#pragma unroll
    for (int j = 0; j < 8; ++j) {
        __bf16 hh = (__bf16)v[j];
        h[j] = hh;
        l[j] = (__bf16)(v[j] - (float)hh);
    }
}

// ---------------- small precompute kernels ----------------

__global__ void k_zero(int* base) {
    int i = threadIdx.x;
    for (int k = i; k < 2304; k += 256) base[k] = 0;
}

__global__ __launch_bounds__(64) void k_emb_scores(const float* __restrict__ emb,
                                                   const float* __restrict__ att_em_i,
                                                   const float* __restrict__ att_em_j,
                                                   float* __restrict__ eemi,
                                                   float* __restrict__ eemj) {
    int n = blockIdx.x;
    int lane = threadIdx.x;
    const float* er = emb + (size_t)n * D_;
    float e0 = er[lane], e1 = er[lane + 64];
    float si = e0 * att_em_i[lane] + e1 * att_em_i[lane + 64];
    float sj = e0 * att_em_j[lane] + e1 * att_em_j[lane + 64];
    for (int off = 32; off > 0; off >>= 1) {
        si += __shfl_down(si, off);
        sj += __shfl_down(sj, off);
    }
    if (lane == 0) { eemi[n] = si; eemj[n] = sj; }
}

__global__ void k_gvec(const float* __restrict__ f_w2, const float* __restrict__ f_b2,
                       const float* __restrict__ out_w, const float* __restrict__ out_b,
                       float* __restrict__ g, float* __restrict__ c0) {
    int j = threadIdx.x;  // 128
    float s = 0.f;
    for (int k = 0; k < D_; ++k) s += out_w[k] * f_w2[k * D_ + j];
    g[j] = s;
    if (j == 0) {
        float c = out_b[0];
        for (int k = 0; k < D_; ++k) c += out_w[k] * f_b2[k];
        *c0 = c;
    }
}

// split weights into bf16 hi/lo: wcat[256][128] = [lin_w ; v_w], f1[128][256] = f_w1
__global__ void k_wprep(const float* __restrict__ lin_w, const float* __restrict__ v_w,
                        const float* __restrict__ f_w1,
                        __bf16* __restrict__ wcat_h, __bf16* __restrict__ wcat_l,
                        __bf16* __restrict__ f1_h, __bf16* __restrict__ f1_l) {
    int i = blockIdx.x * 256 + threadIdx.x;  // 65536 total
    if (i < 32768) {
        float v = (i < 16384) ? lin_w[i] : v_w[i - 16384];
        __bf16 h = (__bf16)v;
        wcat_h[i] = h;
        wcat_l[i] = (__bf16)(v - (float)h);
    } else {
        int j = i - 32768;
        float v = f_w1[j];
        __bf16 h = (__bf16)v;
        f1_h[j] = h;
        f1_l[j] = (__bf16)(v - (float)h);
    }
}

// ---------------- MFMA dual GEMM: [x | t] = data @ [lin_w ; v_w]^T (+v_b on t half) ----------
__global__ __launch_bounds__(512) void k_mfma_dual(const float* __restrict__ data,
                                                   const __bf16* __restrict__ wcat_h,
                                                   const __bf16* __restrict__ wcat_l,
                                                   const float* __restrict__ v_b,
                                                   float* __restrict__ x,
                                                   float* __restrict__ tmat) {
    const int tid = threadIdx.x;
    const int w = tid >> 6;
    const int l = tid & 63;
    bf16x8 Bh[2][4], Bl[2][4];
#pragma unroll
    for (int nt = 0; nt < 2; ++nt) {
        const int n = w * 32 + nt * 16 + (l & 15);
#pragma unroll
        for (int kk = 0; kk < 4; ++kk) {
            const int k = kk * 32 + (l >> 4) * 8;
            Bh[nt][kk] = *(const bf16x8*)&wcat_h[n * D_ + k];
            Bl[nt][kk] = *(const bf16x8*)&wcat_l[n * D_ + k];
        }
    }
    float vb[2] = {0.f, 0.f};
    if (w >= 4) {
#pragma unroll
        for (int nt = 0; nt < 2; ++nt) vb[nt] = v_b[w * 32 + nt * 16 + (l & 15) - 128];
    }
    __shared__ __align__(16) __bf16 dh[32 * D_];
    __shared__ __align__(16) __bf16 dl[32 * D_];
    const int srow = tid >> 4;
    const int skq = (tid & 15) * 8;
    const int sidx = srow * D_ + (skq ^ ((srow & 7) * 8));
    const int nchunks = BN_TOT / 32;
    for (int ch = blockIdx.x; ch < nchunks; ch += gridDim.x) {
        const int row0 = ch * 32;
        {
            const float* src = data + (size_t)(row0 + srow) * D_ + skq;
            float v[8];
            float4 p0 = *(const float4*)src;
            float4 p1 = *(const float4*)(src + 4);
            v[0] = p0.x; v[1] = p0.y; v[2] = p0.z; v[3] = p0.w;
            v[4] = p1.x; v[5] = p1.y; v[6] = p1.z; v[7] = p1.w;
            bf16x8 hv, lv;
            split8(v, hv, lv);
            *(bf16x8*)&dh[sidx] = hv;
            *(bf16x8*)&dl[sidx] = lv;
        }
        __syncthreads();
        f32x4 acc[2][2];
#pragma unroll
        for (int mt = 0; mt < 2; ++mt)
#pragma unroll
            for (int nt = 0; nt < 2; ++nt) acc[mt][nt] = (f32x4){0.f, 0.f, 0.f, 0.f};
#pragma unroll
        for (int mt = 0; mt < 2; ++mt) {
#pragma unroll
            for (int kk = 0; kk < 4; ++kk) {
                const int ai = (mt * 16 + (l & 15)) * D_ + ((kk * 32 + (l >> 4) * 8) ^ ((l & 7) * 8));
                bf16x8 ah = *(const bf16x8*)&dh[ai];
                bf16x8 al = *(const bf16x8*)&dl[ai];
#pragma unroll
                for (int nt = 0; nt < 2; ++nt) {
                    acc[mt][nt] = __builtin_amdgcn_mfma_f32_16x16x32_bf16(ah, Bh[nt][kk], acc[mt][nt], 0, 0, 0);
                    acc[mt][nt] = __builtin_amdgcn_mfma_f32_16x16x32_bf16(ah, Bl[nt][kk], acc[mt][nt], 0, 0, 0);
                    acc[mt][nt] = __builtin_amdgcn_mfma_f32_16x16x32_bf16(al, Bh[nt][kk], acc[mt][nt], 0, 0, 0);
                }
            }
        }
#pragma unroll
        for (int mt = 0; mt < 2; ++mt) {
#pragma unroll
            for (int nt = 0; nt < 2; ++nt) {
                const int col = w * 32 + nt * 16 + (l & 15);
                const int rg = row0 + mt * 16 + (l >> 4) * 4;
                if (w < 4) {
#pragma unroll
                    for (int r = 0; r < 4; ++r)
                        x[(size_t)(rg + r) * D_ + col] = acc[mt][nt][r];
                } else {
                    const int c2 = col - 128;
#pragma unroll
                    for (int r = 0; r < 4; ++r)
                        tmat[(size_t)(rg + r) * D_ + c2] = acc[mt][nt][r] + vb[nt];
                }
            }
        }
        __syncthreads();
    }
}

// ---------------- node attention scores ----------------
__global__ __launch_bounds__(256) void k_scores(const float* __restrict__ x,
                                                const float* __restrict__ att_i,
                                                const float* __restrict__ att_j,
                                                const float* __restrict__ eemi,
                                                const float* __restrict__ eemj,
                                                float* __restrict__ ni, float* __restrict__ nj) {
    const int wid = threadIdx.x >> 6;
    const int lane = threadIdx.x & 63;
    const int row = blockIdx.x * 4 + wid;
    const float* xr = x + (size_t)row * D_;
    float x0 = xr[lane], x1 = xr[lane + 64];
    float si = x0 * att_i[lane] + x1 * att_i[lane + 64];
    float sj = x0 * att_j[lane] + x1 * att_j[lane + 64];
    for (int off = 32; off > 0; off >>= 1) {
        si += __shfl_down(si, off);
        sj += __shfl_down(sj, off);
    }
    if (lane == 0) {
        int n = row % N_;
        ni[row] = si + eemi[n];
        nj[row] = sj + eemj[n];
    }
}

// ---------------- CSR build ----------------
__global__ void k_count(const int* __restrict__ ei, int* __restrict__ offs) {
    int e = blockIdx.x * blockDim.x + threadIdx.x;
    if (e < E_) atomicAdd(&offs[ei[E_ + e] + 1], 1);
}

__global__ __launch_bounds__(1024) void k_scan(int* __restrict__ offs) {
    __shared__ int s[N_ + 1];
    int tid = threadIdx.x;
    if (tid <= N_) s[tid] = offs[tid];
    __syncthreads();
    for (int off = 1; off <= N_; off <<= 1) {
        int v = 0;
        if (tid <= N_) { v = s[tid]; if (tid >= off) v += s[tid - off]; }
        __syncthreads();
        if (tid <= N_) s[tid] = v;
        __syncthreads();
    }
    if (tid <= N_) offs[tid] = s[tid];
}

__global__ void k_scatter(const int* __restrict__ ei, const int* __restrict__ offs,
                          int* __restrict__ cursor, int* __restrict__ csr_src) {
    int e = blockIdx.x * blockDim.x + threadIdx.x;
    if (e < E_) {
        int dn = ei[E_ + e];
        int pos = offs[dn] + atomicAdd(&cursor[dn], 1);
        csr_src[pos] = ei[e];
    }
}

// ---------------- edge softmax: one WAVE per (b,i) ----------------
__global__ __launch_bounds__(256) void k_edge_w(const float* __restrict__ ni,
                                                const float* __restrict__ nj,
                                                const int* __restrict__ offs,
                                                const int* __restrict__ csr_src,
                                                float* __restrict__ exbuf,
                                                float* __restrict__ selfex,
                                                float* __restrict__ denomv) {
    const int wid = threadIdx.x >> 6;
    const int lane = threadIdx.x & 63;
    const int bid = blockIdx.x * 4 + wid;
    const int b = bid / N_;
    const int i = bid - b * N_;
    const int base = b * N_;
    const int e0 = offs[i], e1 = offs[i + 1];
    const float nii = ni[bid];
    const float aself = leaky(nii + nj[bid]);
    float amax = aself;
    for (int e = e0 + lane; e < e1; e += 64) {
        int s = csr_src[e];
        amax = fmaxf(amax, leaky(nii + nj[base + s]));
    }
    for (int off = 32; off > 0; off >>= 1) amax = fmaxf(amax, __shfl_xor(amax, off));
    float sum = 0.f;
    if (lane == 0) {
        float se = __expf(aself - amax);
        selfex[bid] = se;
        sum = se;
    }
    for (int e = e0 + lane; e < e1; e += 64) {
        int s = csr_src[e];
        float ex = __expf(leaky(nii + nj[base + s]) - amax);
        exbuf[(size_t)b * E_ + e] = ex;
        sum += ex;
    }
    for (int off = 32; off > 0; off >>= 1) sum += __shfl_xor(sum, off);
    if (lane == 0) denomv[bid] = sum;
}

// ---------------- SpMM gather-aggregate ----------------
__global__ __launch_bounds__(256) void k_spmm(const float* __restrict__ x,
                                              const int* __restrict__ offs,
                                              const int* __restrict__ csr_src,
                                              const float* __restrict__ exbuf,
                                              const float* __restrict__ selfex,
                                              const float* __restrict__ denomv,
                                              const float* __restrict__ gnn_bias,
                                              float* __restrict__ agg) {
    constexpr int CAP = 256;
    __shared__ int s_lds[2][CAP];
    __shared__ float w_lds[2][CAP];
    const int swz = (blockIdx.x & 7) * 4000 + (blockIdx.x >> 3);
    const int half = threadIdx.x >> 7;
    const int d = threadIdx.x & 127;
    const int bid = swz * 2 + half;
    const int b = bid / N_;
    const int i = bid - b * N_;
    const int base = b * N_;
    const int e0 = offs[i];
    const int deg = offs[i + 1] - e0;
    const int stg = deg < CAP ? deg : CAP;
    for (int k = d; k < stg; k += 128) {
        s_lds[half][k] = csr_src[e0 + k];
        w_lds[half][k] = exbuf[(size_t)b * E_ + e0 + k];
    }
    __syncthreads();
    float acc = selfex[bid] * x[(size_t)bid * D_ + d];
    int k = 0;
    for (; k + 4 <= stg; k += 4) {
        int s0 = s_lds[half][k], s1 = s_lds[half][k + 1], s2 = s_lds[half][k + 2], s3 = s_lds[half][k + 3];
        float w0 = w_lds[half][k], w1 = w_lds[half][k + 1], w2 = w_lds[half][k + 2], w3 = w_lds[half][k + 3];
        float x0 = x[(size_t)(base + s0) * D_ + d];
        float x1 = x[(size_t)(base + s1) * D_ + d];
        float x2 = x[(size_t)(base + s2) * D_ + d];
        float x3 = x[(size_t)(base + s3) * D_ + d];
        acc += w0 * x0 + w1 * x1 + w2 * x2 + w3 * x3;
    }
    for (; k < stg; ++k)
        acc += w_lds[half][k] * x[(size_t)(base + s_lds[half][k]) * D_ + d];
    for (int e = e0 + CAP; e < e0 + deg; ++e) {
        int s = csr_src[e];
        acc += exbuf[(size_t)b * E_ + e] * x[(size_t)(base + s) * D_ + d];
    }
    agg[(size_t)bid * D_ + d] = acc / denomv[bid] + gnn_bias[d];
}

// ---------------- BatchNorm statistics: two-stage, no atomic contention ----------------
// Stage 1: 1024 blocks x 256 thr. Thread (blk, g=tid>>5, c4=tid&31) strides rows by 8192,
// float4 loads, LDS-reduce over g, write per-block partials (64 float4: sum | sumsq).
__global__ __launch_bounds__(256) void k_bn_part(const float* __restrict__ agg,
                                                 float* __restrict__ partials) {
    const int g = threadIdx.x >> 5;
    const int c4 = threadIdx.x & 31;
    f32x4 s = (f32x4){0.f, 0.f, 0.f, 0.f};
    f32x4 q = (f32x4){0.f, 0.f, 0.f, 0.f};
    for (int r = blockIdx.x * 8 + g; r < BN_TOT; r += 8192) {
        float4 v = *(const float4*)&agg[(size_t)r * D_ + c4 * 4];
        s.x += v.x; s.y += v.y; s.z += v.z; s.w += v.w;
        q.x += v.x * v.x; q.y += v.y * v.y; q.z += v.z * v.z; q.w += v.w * v.w;
    }
    __shared__ f32x4 ls[8][32];
    __shared__ f32x4 lq[8][32];
    ls[g][c4] = s;
    lq[g][c4] = q;
    __syncthreads();
    if (threadIdx.x < 32) {
        f32x4 ts = ls[0][threadIdx.x];
        f32x4 tq = lq[0][threadIdx.x];
#pragma unroll
        for (int gg = 1; gg < 8; ++gg) {
            f32x4 a = ls[gg][threadIdx.x];
            f32x4 b = lq[gg][threadIdx.x];
            ts.x += a.x; ts.y += a.y; ts.z += a.z; ts.w += a.w;
            tq.x += b.x; tq.y += b.y; tq.z += b.z; tq.w += b.w;
        }
        f32x4* p = (f32x4*)partials + (size_t)blockIdx.x * 64;
        p[threadIdx.x] = ts;
        p[32 + threadIdx.x] = tq;
    }
}

// Stage 2: single 1024-thread block reduces 1024 partials -> scale/shift.
__global__ __launch_bounds__(1024) void k_bn_fin2(const float* __restrict__ partials,
                                                  const float* __restrict__ gamma,
                                                  const float* __restrict__ beta,
                                                  float* __restrict__ scale,
                                                  float* __restrict__ shift) {
    const int d = threadIdx.x & 127;
    const int part = threadIdx.x >> 7;   // 0..7, each covers 128 blocks
    float s = 0.f, q = 0.f;
    for (int blk = part * 128; blk < part * 128 + 128; ++blk) {
        s += partials[(size_t)blk * 256 + d];
        q += partials[(size_t)blk * 256 + 128 + d];
    }
    __shared__ float lss[8][128];
    __shared__ float lqq[8][128];
    lss[part][d] = s;
    lqq[part][d] = q;
    __syncthreads();
    if (threadIdx.x < 128) {
        float ts = 0.f, tq = 0.f;
#pragma unroll
        for (int p = 0; p < 8; ++p) { ts += lss[p][d]; tq += lqq[p][d]; }
        float mu = ts * (1.f / BN_TOT);
        float var = tq * (1.f / BN_TOT) - mu * mu;
        float sc = gamma[d] * rsqrtf(var + BN_EPS);
        scale[d] = sc;
        shift[d] = beta[d] - mu * sc;
    }
}

// ---------------- MFMA fusion ----------------
__global__ __launch_bounds__(512) void k_mfma_fusion(const float* __restrict__ agg,
                                                     const float* __restrict__ tmat,
                                                     const __bf16* __restrict__ f1_h,
                                                     const __bf16* __restrict__ f1_l,
                                                     const float* __restrict__ f_b1,
                                                     const float* __restrict__ scale,
                                                     const float* __restrict__ shift,
                                                     const float* __restrict__ g,
                                                     const float* __restrict__ c0p,
                                                     float* __restrict__ out) {
    const int tid = threadIdx.x;
    const int w = tid >> 6;
    const int l = tid & 63;
    const float c0v = *c0p;
    bf16x8 Fh[8], Fl[8];
    const int ncol = w * 16 + (l & 15);
#pragma unroll
    for (int kk = 0; kk < 8; ++kk) {
        const int k = kk * 32 + (l >> 4) * 8;
        Fh[kk] = *(const bf16x8*)&f1_h[ncol * 256 + k];
        Fl[kk] = *(const bf16x8*)&f1_l[ncol * 256 + k];
    }
    const float b1c = f_b1[ncol];
    const float gc = g[ncol];
    __shared__ __align__(16) __bf16 ch_[32 * 256];
    __shared__ __align__(16) __bf16 cl_[32 * 256];
    __shared__ float part[8][32];
    const int srow = tid >> 4;
    const int scb = (tid & 15) * 16;
    const bool isagg = scb < 128;
    float4 sc4[4], sh4[4];
    if (isagg) {
#pragma unroll
        for (int q = 0; q < 4; ++q) {
            sc4[q] = *(const float4*)&scale[scb + q * 4];
            sh4[q] = *(const float4*)&shift[scb + q * 4];
        }
    }
    const int nchunks = BN_TOT / 32;
    for (int chk = blockIdx.x; chk < nchunks; chk += gridDim.x) {
        const int row0 = chk * 32;
        {
            const float* srcp = isagg ? (agg + (size_t)(row0 + srow) * D_ + scb)
                                      : (tmat + (size_t)(row0 + srow) * D_ + (scb - 128));
            float v[16];
#pragma unroll
            for (int q = 0; q < 4; ++q) {
                float4 p = *(const float4*)(srcp + q * 4);
                if (isagg) {
                    p.x = fmaxf(p.x * sc4[q].x + sh4[q].x, 0.f);
                    p.y = fmaxf(p.y * sc4[q].y + sh4[q].y, 0.f);
                    p.z = fmaxf(p.z * sc4[q].z + sh4[q].z, 0.f);
                    p.w = fmaxf(p.w * sc4[q].w + sh4[q].w, 0.f);
                }
                v[q * 4 + 0] = p.x; v[q * 4 + 1] = p.y; v[q * 4 + 2] = p.z; v[q * 4 + 3] = p.w;
            }
#pragma unroll
            for (int hh = 0; hh < 2; ++hh) {
                bf16x8 hv, lv;
                split8(v + hh * 8, hv, lv);
                const int c = scb + hh * 8;
                const int idx = srow * 256 + (c ^ ((srow & 7) * 8));
                *(bf16x8*)&ch_[idx] = hv;
                *(bf16x8*)&cl_[idx] = lv;
            }
        }
        __syncthreads();
#pragma unroll
        for (int mt = 0; mt < 2; ++mt) {
            f32x4 acc = (f32x4){0.f, 0.f, 0.f, 0.f};
#pragma unroll
            for (int kk = 0; kk < 8; ++kk) {
                const int ai = (mt * 16 + (l & 15)) * 256 + ((kk * 32 + (l >> 4) * 8) ^ ((l & 7) * 8));
                bf16x8 ah = *(const bf16x8*)&ch_[ai];
                bf16x8 al = *(const bf16x8*)&cl_[ai];
                acc = __builtin_amdgcn_mfma_f32_16x16x32_bf16(ah, Fh[kk], acc, 0, 0, 0);
                acc = __builtin_amdgcn_mfma_f32_16x16x32_bf16(ah, Fl[kk], acc, 0, 0, 0);
                acc = __builtin_amdgcn_mfma_f32_16x16x32_bf16(al, Fh[kk], acc, 0, 0, 0);
            }
            float p[4];
#pragma unroll
            for (int r = 0; r < 4; ++r) p[r] = fmaxf(acc[r] + b1c, 0.f) * gc;
#pragma unroll
            for (int r = 0; r < 4; ++r) {
                p[r] += __shfl_xor(p[r], 1);
                p[r] += __shfl_xor(p[r], 2);
                p[r] += __shfl_xor(p[r], 4);
                p[r] += __shfl_xor(p[r], 8);
            }
            if ((l & 15) == 0) {
#pragma unroll
                for (int r = 0; r < 4; ++r) part[w][mt * 16 + (l >> 4) * 4 + r] = p[r];
            }
        }
        __syncthreads();
        if (tid < 32) {
            float s = c0v;
#pragma unroll
            for (int ww = 0; ww < 8; ++ww) s += part[ww][tid];
            out[row0 + tid] = s;
        }
        __syncthreads();
    }
}

// ---------------- launch ----------------
extern "C" void kernel_launch(void* const* d_in, const int* in_sizes, int n_in,
                              void* d_out, int out_size, void* d_ws, size_t ws_size,
                              hipStream_t stream) {
    const float* data     = (const float*)d_in[0];
    const int*   ei       = (const int*)d_in[1];
    const float* emb      = (const float*)d_in[2];
    const float* lin_w    = (const float*)d_in[3];
    const float* att_i    = (const float*)d_in[4];
    const float* att_j    = (const float*)d_in[5];
    const float* att_em_i = (const float*)d_in[6];
    const float* att_em_j = (const float*)d_in[7];
    const float* gnn_bias = (const float*)d_in[8];
    const float* bn_gamma = (const float*)d_in[9];
    const float* bn_beta  = (const float*)d_in[10];
    // q_w,q_b,k_w,k_b,temperature dead (W=1 -> softmax over single element -> attn==1)
    const float* v_w      = (const float*)d_in[15];
    const float* v_b      = (const float*)d_in[16];
    const float* f_w1     = (const float*)d_in[18];
    const float* f_b1     = (const float*)d_in[19];
    const float* f_w2     = (const float*)d_in[20];
    const float* f_b2     = (const float*)d_in[21];
    const float* out_w    = (const float*)d_in[22];
    const float* out_b    = (const float*)d_in[23];
    float* out = (float*)d_out;

    float* ws = (float*)d_ws;
    float* x      = ws;                                 // BN*D
    float* tmat   = x + (size_t)BN_TOT * D_;            // BN*D
    float* agg    = tmat + (size_t)BN_TOT * D_;         // BN*D
    float* ni     = agg + (size_t)BN_TOT * D_;          // BN
    float* nj     = ni + BN_TOT;                        // BN
    float* eemi   = nj + BN_TOT;                        // N
    float* eemj   = eemi + N_;                          // N
    float* g      = eemj + N_;                          // D
    float* c0     = g + D_;                             // 1 (pad 8)
    float* scale  = c0 + 8;                             // D
    float* shift  = scale + D_;                         // D
    int* offs     = (int*)(shift + D_);                 // 1024 [zeroed]
    int* cursor   = offs + 1024;                        // 1024 [zeroed]
    float* bn_sum = (float*)(cursor + 1024);            // 128  [zeroed, unused now]
    float* bn_sq  = bn_sum + D_;                        // 128  [zeroed, unused now]
    int* csr_src  = (int*)(bn_sq + D_);                 // E
    float* exbuf  = (float*)(csr_src + E_);             // B*E
    float* selfex = exbuf + (size_t)B_ * E_;            // BN
    float* denomv = selfex + BN_TOT;                    // BN
    __bf16* wcat_h = (__bf16*)(denomv + BN_TOT);        // 256*128
    __bf16* wcat_l = wcat_h + 256 * 128;                // 256*128
    __bf16* f1_h   = wcat_l + 256 * 128;                // 128*256
    __bf16* f1_l   = f1_h + 128 * 256;                  // 128*256
    float* partials = (float*)(f1_l + 128 * 256);       // 1024*256 floats = 1 MB

    k_zero<<<1, 256, 0, stream>>>(offs);
    k_emb_scores<<<N_, 64, 0, stream>>>(emb, att_em_i, att_em_j, eemi, eemj);
    k_gvec<<<1, 128, 0, stream>>>(f_w2, f_b2, out_w, out_b, g, c0);
    k_wprep<<<256, 256, 0, stream>>>(lin_w, v_w, f_w1, wcat_h, wcat_l, f1_h, f1_l);
    k_mfma_dual<<<512, 512, 0, stream>>>(data, wcat_h, wcat_l, v_b, x, tmat);
    k_scores<<<BN_TOT / 4, 256, 0, stream>>>(x, att_i, att_j, eemi, eemj, ni, nj);
    k_count<<<(E_ + 255) / 256, 256, 0, stream>>>(ei, offs);
    k_scan<<<1, 1024, 0, stream>>>(offs);
    k_scatter<<<(E_ + 255) / 256, 256, 0, stream>>>(ei, offs, cursor, csr_src);
    k_edge_w<<<BN_TOT / 4, 256, 0, stream>>>(ni, nj, offs, csr_src, exbuf, selfex, denomv);
    k_spmm<<<BN_TOT / 2, 256, 0, stream>>>(x, offs, csr_src, exbuf, selfex, denomv, gnn_bias, agg);
    k_bn_part<<<1024, 256, 0, stream>>>(agg, partials);
    k_bn_fin2<<<1, 1024, 0, stream>>>(partials, bn_gamma, bn_beta, scale, shift);
    k_mfma_fusion<<<512, 512, 0, stream>>>(agg, tmat, f1_h, f1_l, f_b1, scale, shift, g, c0, out);
}

// Round 5
// 215.944 us; speedup vs baseline: 2.4126x; 1.0176x over previous
//
#include <hip/hip_runtime.h>
#include <math.h>

constexpr int B_ = 64;
constexpr int N_ = 1000;
constexpr int D_ = 128;
constexpr int E_ = 20000;
constexpr int BN_TOT = B_ * N_;
constexpr float BN_EPS = 1e-5f;
constexpr float NEG_SLOPE = 0.2f;

typedef __attribute__((ext_vector_type(8))) __bf16 bf16x8;
typedef __attribute__((ext_vector_type(4))) float f32x4;

__device__ __forceinline__ float leaky(float a) { return a >= 0.f ? a : NEG_SLOPE * a; }

__device__ __forceinline__ void split8(const float* v, bf16x8& h, bf16x8& l) {
#pragma unroll
    for (int j = 0; j < 8; ++j) {
        __bf16 hh = (__bf16)v[j];
        h[j] = hh;
        l[j] = (__bf16)(v[j] - (float)hh);
    }
}

// ---------------- small precompute kernels ----------------

__global__ void k_zero(int* base) {
    int i = threadIdx.x;
    for (int k = i; k < 2304; k += 256) base[k] = 0;
}

__global__ __launch_bounds__(64) void k_emb_scores(const float* __restrict__ emb,
                                                   const float* __restrict__ att_em_i,
                                                   const float* __restrict__ att_em_j,
                                                   float* __restrict__ eemi,
                                                   float* __restrict__ eemj) {
    int n = blockIdx.x;
    int lane = threadIdx.x;
    const float* er = emb + (size_t)n * D_;
    float e0 = er[lane], e1 = er[lane + 64];
    float si = e0 * att_em_i[lane] + e1 * att_em_i[lane + 64];
    float sj = e0 * att_em_j[lane] + e1 * att_em_j[lane + 64];
    for (int off = 32; off > 0; off >>= 1) {
        si += __shfl_down(si, off);
        sj += __shfl_down(sj, off);
    }
    if (lane == 0) { eemi[n] = si; eemj[n] = sj; }
}

__global__ void k_gvec(const float* __restrict__ f_w2, const float* __restrict__ f_b2,
                       const float* __restrict__ out_w, const float* __restrict__ out_b,
                       float* __restrict__ g, float* __restrict__ c0) {
    int j = threadIdx.x;  // 128
    float s = 0.f;
    for (int k = 0; k < D_; ++k) s += out_w[k] * f_w2[k * D_ + j];
    g[j] = s;
    if (j == 0) {
        float c = out_b[0];
        for (int k = 0; k < D_; ++k) c += out_w[k] * f_b2[k];
        *c0 = c;
    }
}

// split weights into bf16 hi/lo: wcat[256][128] = [lin_w ; v_w], f1[128][256] = f_w1
__global__ void k_wprep(const float* __restrict__ lin_w, const float* __restrict__ v_w,
                        const float* __restrict__ f_w1,
                        __bf16* __restrict__ wcat_h, __bf16* __restrict__ wcat_l,
                        __bf16* __restrict__ f1_h, __bf16* __restrict__ f1_l) {
    int i = blockIdx.x * 256 + threadIdx.x;  // 65536 total
    if (i < 32768) {
        float v = (i < 16384) ? lin_w[i] : v_w[i - 16384];
        __bf16 h = (__bf16)v;
        wcat_h[i] = h;
        wcat_l[i] = (__bf16)(v - (float)h);
    } else {
        int j = i - 32768;
        float v = f_w1[j];
        __bf16 h = (__bf16)v;
        f1_h[j] = h;
        f1_l[j] = (__bf16)(v - (float)h);
    }
}

// ---------------- MFMA dual GEMM: [x | t] = data @ [lin_w ; v_w]^T (+v_b on t half) ----------
__global__ __launch_bounds__(512) void k_mfma_dual(const float* __restrict__ data,
                                                   const __bf16* __restrict__ wcat_h,
                                                   const __bf16* __restrict__ wcat_l,
                                                   const float* __restrict__ v_b,
                                                   float* __restrict__ x,
                                                   float* __restrict__ tmat) {
    const int tid = threadIdx.x;
    const int w = tid >> 6;
    const int l = tid & 63;
    bf16x8 Bh[2][4], Bl[2][4];
#pragma unroll
    for (int nt = 0; nt < 2; ++nt) {
        const int n = w * 32 + nt * 16 + (l & 15);
#pragma unroll
        for (int kk = 0; kk < 4; ++kk) {
            const int k = kk * 32 + (l >> 4) * 8;
            Bh[nt][kk] = *(const bf16x8*)&wcat_h[n * D_ + k];
            Bl[nt][kk] = *(const bf16x8*)&wcat_l[n * D_ + k];
        }
    }
    float vb[2] = {0.f, 0.f};
    if (w >= 4) {
#pragma unroll
        for (int nt = 0; nt < 2; ++nt) vb[nt] = v_b[w * 32 + nt * 16 + (l & 15) - 128];
    }
    __shared__ __align__(16) __bf16 dh[32 * D_];
    __shared__ __align__(16) __bf16 dl[32 * D_];
    const int srow = tid >> 4;
    const int skq = (tid & 15) * 8;
    const int sidx = srow * D_ + (skq ^ ((srow & 7) * 8));
    const int nchunks = BN_TOT / 32;
    for (int ch = blockIdx.x; ch < nchunks; ch += gridDim.x) {
        const int row0 = ch * 32;
        {
            const float* src = data + (size_t)(row0 + srow) * D_ + skq;
            float v[8];
            float4 p0 = *(const float4*)src;
            float4 p1 = *(const float4*)(src + 4);
            v[0] = p0.x; v[1] = p0.y; v[2] = p0.z; v[3] = p0.w;
            v[4] = p1.x; v[5] = p1.y; v[6] = p1.z; v[7] = p1.w;
            bf16x8 hv, lv;
            split8(v, hv, lv);
            *(bf16x8*)&dh[sidx] = hv;
            *(bf16x8*)&dl[sidx] = lv;
        }
        __syncthreads();
        f32x4 acc[2][2];
#pragma unroll
        for (int mt = 0; mt < 2; ++mt)
#pragma unroll
            for (int nt = 0; nt < 2; ++nt) acc[mt][nt] = (f32x4){0.f, 0.f, 0.f, 0.f};
#pragma unroll
        for (int mt = 0; mt < 2; ++mt) {
#pragma unroll
            for (int kk = 0; kk < 4; ++kk) {
                const int ai = (mt * 16 + (l & 15)) * D_ + ((kk * 32 + (l >> 4) * 8) ^ ((l & 7) * 8));
                bf16x8 ah = *(const bf16x8*)&dh[ai];
                bf16x8 al = *(const bf16x8*)&dl[ai];
#pragma unroll
                for (int nt = 0; nt < 2; ++nt) {
                    acc[mt][nt] = __builtin_amdgcn_mfma_f32_16x16x32_bf16(ah, Bh[nt][kk], acc[mt][nt], 0, 0, 0);
                    acc[mt][nt] = __builtin_amdgcn_mfma_f32_16x16x32_bf16(ah, Bl[nt][kk], acc[mt][nt], 0, 0, 0);
                    acc[mt][nt] = __builtin_amdgcn_mfma_f32_16x16x32_bf16(al, Bh[nt][kk], acc[mt][nt], 0, 0, 0);
                }
            }
        }
#pragma unroll
        for (int mt = 0; mt < 2; ++mt) {
#pragma unroll
            for (int nt = 0; nt < 2; ++nt) {
                const int col = w * 32 + nt * 16 + (l & 15);
                const int rg = row0 + mt * 16 + (l >> 4) * 4;
                if (w < 4) {
#pragma unroll
                    for (int r = 0; r < 4; ++r)
                        x[(size_t)(rg + r) * D_ + col] = acc[mt][nt][r];
                } else {
                    const int c2 = col - 128;
#pragma unroll
                    for (int r = 0; r < 4; ++r)
                        tmat[(size_t)(rg + r) * D_ + c2] = acc[mt][nt][r] + vb[nt];
                }
            }
        }
        __syncthreads();
    }
}

// ---------------- node attention scores ----------------
__global__ __launch_bounds__(256) void k_scores(const float* __restrict__ x,
                                                const float* __restrict__ att_i,
                                                const float* __restrict__ att_j,
                                                const float* __restrict__ eemi,
                                                const float* __restrict__ eemj,
                                                float* __restrict__ ni, float* __restrict__ nj) {
    const int wid = threadIdx.x >> 6;
    const int lane = threadIdx.x & 63;
    const int row = blockIdx.x * 4 + wid;
    const float* xr = x + (size_t)row * D_;
    float x0 = xr[lane], x1 = xr[lane + 64];
    float si = x0 * att_i[lane] + x1 * att_i[lane + 64];
    float sj = x0 * att_j[lane] + x1 * att_j[lane + 64];
    for (int off = 32; off > 0; off >>= 1) {
        si += __shfl_down(si, off);
        sj += __shfl_down(sj, off);
    }
    if (lane == 0) {
        int n = row % N_;
        ni[row] = si + eemi[n];
        nj[row] = sj + eemj[n];
    }
}

// ---------------- CSR build ----------------
__global__ void k_count(const int* __restrict__ ei, int* __restrict__ offs) {
    int e = blockIdx.x * blockDim.x + threadIdx.x;
    if (e < E_) atomicAdd(&offs[ei[E_ + e] + 1], 1);
}

__global__ __launch_bounds__(1024) void k_scan(int* __restrict__ offs) {
    __shared__ int s[N_ + 1];
    int tid = threadIdx.x;
    if (tid <= N_) s[tid] = offs[tid];
    __syncthreads();
    for (int off = 1; off <= N_; off <<= 1) {
        int v = 0;
        if (tid <= N_) { v = s[tid]; if (tid >= off) v += s[tid - off]; }
        __syncthreads();
        if (tid <= N_) s[tid] = v;
        __syncthreads();
    }
    if (tid <= N_) offs[tid] = s[tid];
}

__global__ void k_scatter(const int* __restrict__ ei, const int* __restrict__ offs,
                          int* __restrict__ cursor, int* __restrict__ csr_src) {
    int e = blockIdx.x * blockDim.x + threadIdx.x;
    if (e < E_) {
        int dn = ei[E_ + e];
        int pos = offs[dn] + atomicAdd(&cursor[dn], 1);
        csr_src[pos] = ei[e];
    }
}

// ---------------- edge softmax: one WAVE per (b,i) ----------------
__global__ __launch_bounds__(256) void k_edge_w(const float* __restrict__ ni,
                                                const float* __restrict__ nj,
                                                const int* __restrict__ offs,
                                                const int* __restrict__ csr_src,
                                                float* __restrict__ exbuf,
                                                float* __restrict__ selfex,
                                                float* __restrict__ denomv) {
    const int wid = threadIdx.x >> 6;
    const int lane = threadIdx.x & 63;
    const int bid = blockIdx.x * 4 + wid;
    const int b = bid / N_;
    const int i = bid - b * N_;
    const int base = b * N_;
    const int e0 = offs[i], e1 = offs[i + 1];
    const float nii = ni[bid];
    const float aself = leaky(nii + nj[bid]);
    float amax = aself;
    for (int e = e0 + lane; e < e1; e += 64) {
        int s = csr_src[e];
        amax = fmaxf(amax, leaky(nii + nj[base + s]));
    }
    for (int off = 32; off > 0; off >>= 1) amax = fmaxf(amax, __shfl_xor(amax, off));
    float sum = 0.f;
    if (lane == 0) {
        float se = __expf(aself - amax);
        selfex[bid] = se;
        sum = se;
    }
    for (int e = e0 + lane; e < e1; e += 64) {
        int s = csr_src[e];
        float ex = __expf(leaky(nii + nj[base + s]) - amax);
        exbuf[(size_t)b * E_ + e] = ex;
        sum += ex;
    }
    for (int off = 32; off > 0; off >>= 1) sum += __shfl_xor(sum, off);
    if (lane == 0) denomv[bid] = sum;
}

// ---------------- SpMM gather-aggregate: one WAVE per segment, float2 lanes, batch-8 ----------
__global__ __launch_bounds__(256) void k_spmm(const float* __restrict__ x,
                                              const int* __restrict__ offs,
                                              const int* __restrict__ csr_src,
                                              const float* __restrict__ exbuf,
                                              const float* __restrict__ selfex,
                                              const float* __restrict__ denomv,
                                              const float* __restrict__ gnn_bias,
                                              float* __restrict__ agg) {
    constexpr int CAP = 128;
    __shared__ int s_lds[4][CAP];
    __shared__ float w_lds[4][CAP];
    // 16000 blocks = 8 XCD * 2000; each XCD gets a contiguous 4-batch-pair slice (L2-resident x)
    const int swz = (blockIdx.x & 7) * 2000 + (blockIdx.x >> 3);
    const int w = threadIdx.x >> 6;     // wave id = segment within block
    const int l = threadIdx.x & 63;     // lane = 2 channels (float2)
    const int bid = swz * 4 + w;
    const int b = bid / N_;
    const int i = bid - b * N_;
    const int base = b * N_;
    const int e0 = offs[i];
    const int deg = offs[i + 1] - e0;
    const int stg = deg < CAP ? deg : CAP;
    for (int k = l; k < stg; k += 64) {
        s_lds[w][k] = csr_src[e0 + k];
        w_lds[w][k] = exbuf[(size_t)b * E_ + e0 + k];
    }
    __syncthreads();
    const float2* x2 = (const float2*)x;
    float2 acc;
    {
        float se = selfex[bid];
        float2 xv = x2[(size_t)bid * 64 + l];
        acc.x = se * xv.x;
        acc.y = se * xv.y;
    }
    int k = 0;
    for (; k + 8 <= stg; k += 8) {
        float2 v[8];
        float wg[8];
#pragma unroll
        for (int j = 0; j < 8; ++j) {
            int s = s_lds[w][k + j];
            wg[j] = w_lds[w][k + j];
            v[j] = x2[(size_t)(base + s) * 64 + l];
        }
#pragma unroll
        for (int j = 0; j < 8; ++j) {
            acc.x += wg[j] * v[j].x;
            acc.y += wg[j] * v[j].y;
        }
    }
    for (; k < stg; ++k) {
        int s = s_lds[w][k];
        float wg = w_lds[w][k];
        float2 xv = x2[(size_t)(base + s) * 64 + l];
        acc.x += wg * xv.x;
        acc.y += wg * xv.y;
    }
    for (int e = e0 + CAP; e < e0 + deg; ++e) {   // overflow fallback
        int s = csr_src[e];
        float wg = exbuf[(size_t)b * E_ + e];
        float2 xv = x2[(size_t)(base + s) * 64 + l];
        acc.x += wg * xv.x;
        acc.y += wg * xv.y;
    }
    const float dn = 1.f / denomv[bid];
    float2 gb = ((const float2*)gnn_bias)[l];
    float2 o;
    o.x = acc.x * dn + gb.x;
    o.y = acc.y * dn + gb.y;
    ((float2*)agg)[(size_t)bid * 64 + l] = o;
}

// ---------------- BatchNorm statistics: two-stage ----------------
__global__ __launch_bounds__(256) void k_bn_part(const float* __restrict__ agg,
                                                 float* __restrict__ partials) {
    const int g = threadIdx.x >> 5;
    const int c4 = threadIdx.x & 31;
    f32x4 s = (f32x4){0.f, 0.f, 0.f, 0.f};
    f32x4 q = (f32x4){0.f, 0.f, 0.f, 0.f};
    for (int r = blockIdx.x * 8 + g; r < BN_TOT; r += 8192) {
        float4 v = *(const float4*)&agg[(size_t)r * D_ + c4 * 4];
        s.x += v.x; s.y += v.y; s.z += v.z; s.w += v.w;
        q.x += v.x * v.x; q.y += v.y * v.y; q.z += v.z * v.z; q.w += v.w * v.w;
    }
    __shared__ f32x4 ls[8][32];
    __shared__ f32x4 lq[8][32];
    ls[g][c4] = s;
    lq[g][c4] = q;
    __syncthreads();
    if (threadIdx.x < 32) {
        f32x4 ts = ls[0][threadIdx.x];
        f32x4 tq = lq[0][threadIdx.x];
#pragma unroll
        for (int gg = 1; gg < 8; ++gg) {
            f32x4 a = ls[gg][threadIdx.x];
            f32x4 b = lq[gg][threadIdx.x];
            ts.x += a.x; ts.y += a.y; ts.z += a.z; ts.w += a.w;
            tq.x += b.x; tq.y += b.y; tq.z += b.z; tq.w += b.w;
        }
        f32x4* p = (f32x4*)partials + (size_t)blockIdx.x * 64;
        p[threadIdx.x] = ts;
        p[32 + threadIdx.x] = tq;
    }
}

__global__ __launch_bounds__(1024) void k_bn_fin2(const float* __restrict__ partials,
                                                  const float* __restrict__ gamma,
                                                  const float* __restrict__ beta,
                                                  float* __restrict__ scale,
                                                  float* __restrict__ shift) {
    const int d = threadIdx.x & 127;
    const int part = threadIdx.x >> 7;
    float s = 0.f, q = 0.f;
    for (int blk = part * 128; blk < part * 128 + 128; ++blk) {
        s += partials[(size_t)blk * 256 + d];
        q += partials[(size_t)blk * 256 + 128 + d];
    }
    __shared__ float lss[8][128];
    __shared__ float lqq[8][128];
    lss[part][d] = s;
    lqq[part][d] = q;
    __syncthreads();
    if (threadIdx.x < 128) {
        float ts = 0.f, tq = 0.f;
#pragma unroll
        for (int p = 0; p < 8; ++p) { ts += lss[p][d]; tq += lqq[p][d]; }
        float mu = ts * (1.f / BN_TOT);
        float var = tq * (1.f / BN_TOT) - mu * mu;
        float sc = gamma[d] * rsqrtf(var + BN_EPS);
        scale[d] = sc;
        shift[d] = beta[d] - mu * sc;
    }
}

// ---------------- MFMA fusion ----------------
__global__ __launch_bounds__(512) void k_mfma_fusion(const float* __restrict__ agg,
                                                     const float* __restrict__ tmat,
                                                     const __bf16* __restrict__ f1_h,
                                                     const __bf16* __restrict__ f1_l,
                                                     const float* __restrict__ f_b1,
                                                     const float* __restrict__ scale,
                                                     const float* __restrict__ shift,
                                                     const float* __restrict__ g,
                                                     const float* __restrict__ c0p,
                                                     float* __restrict__ out) {
    const int tid = threadIdx.x;
    const int w = tid >> 6;
    const int l = tid & 63;
    const float c0v = *c0p;
    bf16x8 Fh[8], Fl[8];
    const int ncol = w * 16 + (l & 15);
#pragma unroll
    for (int kk = 0; kk < 8; ++kk) {
        const int k = kk * 32 + (l >> 4) * 8;
        Fh[kk] = *(const bf16x8*)&f1_h[ncol * 256 + k];
        Fl[kk] = *(const bf16x8*)&f1_l[ncol * 256 + k];
    }
    const float b1c = f_b1[ncol];
    const float gc = g[ncol];
    __shared__ __align__(16) __bf16 ch_[32 * 256];
    __shared__ __align__(16) __bf16 cl_[32 * 256];
    __shared__ float part[8][32];
    const int srow = tid >> 4;
    const int scb = (tid & 15) * 16;
    const bool isagg = scb < 128;
    float4 sc4[4], sh4[4];
    if (isagg) {
#pragma unroll
        for (int q = 0; q < 4; ++q) {
            sc4[q] = *(const float4*)&scale[scb + q * 4];
            sh4[q] = *(const float4*)&shift[scb + q * 4];
        }
    }
    const int nchunks = BN_TOT / 32;
    for (int chk = blockIdx.x; chk < nchunks; chk += gridDim.x) {
        const int row0 = chk * 32;
        {
            const float* srcp = isagg ? (agg + (size_t)(row0 + srow) * D_ + scb)
                                      : (tmat + (size_t)(row0 + srow) * D_ + (scb - 128));
            float v[16];
#pragma unroll
            for (int q = 0; q < 4; ++q) {
                float4 p = *(const float4*)(srcp + q * 4);
                if (isagg) {
                    p.x = fmaxf(p.x * sc4[q].x + sh4[q].x, 0.f);
                    p.y = fmaxf(p.y * sc4[q].y + sh4[q].y, 0.f);
                    p.z = fmaxf(p.z * sc4[q].z + sh4[q].z, 0.f);
                    p.w = fmaxf(p.w * sc4[q].w + sh4[q].w, 0.f);
                }
                v[q * 4 + 0] = p.x; v[q * 4 + 1] = p.y; v[q * 4 + 2] = p.z; v[q * 4 + 3] = p.w;
            }
#pragma unroll
            for (int hh = 0; hh < 2; ++hh) {
                bf16x8 hv, lv;
                split8(v + hh * 8, hv, lv);
                const int c = scb + hh * 8;
                const int idx = srow * 256 + (c ^ ((srow & 7) * 8));
                *(bf16x8*)&ch_[idx] = hv;
                *(bf16x8*)&cl_[idx] = lv;
            }
        }
        __syncthreads();
#pragma unroll
        for (int mt = 0; mt < 2; ++mt) {
            f32x4 acc = (f32x4){0.f, 0.f, 0.f, 0.f};
#pragma unroll
            for (int kk = 0; kk < 8; ++kk) {
                const int ai = (mt * 16 + (l & 15)) * 256 + ((kk * 32 + (l >> 4) * 8) ^ ((l & 7) * 8));
                bf16x8 ah = *(const bf16x8*)&ch_[ai];
                bf16x8 al = *(const bf16x8*)&cl_[ai];
                acc = __builtin_amdgcn_mfma_f32_16x16x32_bf16(ah, Fh[kk], acc, 0, 0, 0);
                acc = __builtin_amdgcn_mfma_f32_16x16x32_bf16(ah, Fl[kk], acc, 0, 0, 0);
                acc = __builtin_amdgcn_mfma_f32_16x16x32_bf16(al, Fh[kk], acc, 0, 0, 0);
            }
            float p[4];
#pragma unroll
            for (int r = 0; r < 4; ++r) p[r] = fmaxf(acc[r] + b1c, 0.f) * gc;
#pragma unroll
            for (int r = 0; r < 4; ++r) {
                p[r] += __shfl_xor(p[r], 1);
                p[r] += __shfl_xor(p[r], 2);
                p[r] += __shfl_xor(p[r], 4);
                p[r] += __shfl_xor(p[r], 8);
            }
            if ((l & 15) == 0) {
#pragma unroll
                for (int r = 0; r < 4; ++r) part[w][mt * 16 + (l >> 4) * 4 + r] = p[r];
            }
        }
        __syncthreads();
        if (tid < 32) {
            float s = c0v;
#pragma unroll
            for (int ww = 0; ww < 8; ++ww) s += part[ww][tid];
            out[row0 + tid] = s;
        }
        __syncthreads();
    }
}

// ---------------- launch ----------------
extern "C" void kernel_launch(void* const* d_in, const int* in_sizes, int n_in,
                              void* d_out, int out_size, void* d_ws, size_t ws_size,
                              hipStream_t stream) {
    const float* data     = (const float*)d_in[0];
    const int*   ei       = (const int*)d_in[1];
    const float* emb      = (const float*)d_in[2];
    const float* lin_w    = (const float*)d_in[3];
    const float* att_i    = (const float*)d_in[4];
    const float* att_j    = (const float*)d_in[5];
    const float* att_em_i = (const float*)d_in[6];
    const float* att_em_j = (const float*)d_in[7];
    const float* gnn_bias = (const float*)d_in[8];
    const float* bn_gamma = (const float*)d_in[9];
    const float* bn_beta  = (const float*)d_in[10];
    // q_w,q_b,k_w,k_b,temperature dead (W=1 -> softmax over single element -> attn==1)
    const float* v_w      = (const float*)d_in[15];
    const float* v_b      = (const float*)d_in[16];
    const float* f_w1     = (const float*)d_in[18];
    const float* f_b1     = (const float*)d_in[19];
    const float* f_w2     = (const float*)d_in[20];
    const float* f_b2     = (const float*)d_in[21];
    const float* out_w    = (const float*)d_in[22];
    const float* out_b    = (const float*)d_in[23];
    float* out = (float*)d_out;

    float* ws = (float*)d_ws;
    float* x      = ws;                                 // BN*D
    float* tmat   = x + (size_t)BN_TOT * D_;            // BN*D
    float* agg    = tmat + (size_t)BN_TOT * D_;         // BN*D
    float* ni     = agg + (size_t)BN_TOT * D_;          // BN
    float* nj     = ni + BN_TOT;                        // BN
    float* eemi   = nj + BN_TOT;                        // N
    float* eemj   = eemi + N_;                          // N
    float* g      = eemj + N_;                          // D
    float* c0     = g + D_;                             // 1 (pad 8)
    float* scale  = c0 + 8;                             // D
    float* shift  = scale + D_;                         // D
    int* offs     = (int*)(shift + D_);                 // 1024 [zeroed]
    int* cursor   = offs + 1024;                        // 1024 [zeroed]
    float* bn_sum = (float*)(cursor + 1024);            // 128  [zeroed, unused now]
    float* bn_sq  = bn_sum + D_;                        // 128  [zeroed, unused now]
    int* csr_src  = (int*)(bn_sq + D_);                 // E
    float* exbuf  = (float*)(csr_src + E_);             // B*E
    float* selfex = exbuf + (size_t)B_ * E_;            // BN
    float* denomv = selfex + BN_TOT;                    // BN
    __bf16* wcat_h = (__bf16*)(denomv + BN_TOT);        // 256*128
    __bf16* wcat_l = wcat_h + 256 * 128;                // 256*128
    __bf16* f1_h   = wcat_l + 256 * 128;                // 128*256
    __bf16* f1_l   = f1_h + 128 * 256;                  // 128*256
    float* partials = (float*)(f1_l + 128 * 256);       // 1024*256 floats = 1 MB

    k_zero<<<1, 256, 0, stream>>>(offs);
    k_emb_scores<<<N_, 64, 0, stream>>>(emb, att_em_i, att_em_j, eemi, eemj);
    k_gvec<<<1, 128, 0, stream>>>(f_w2, f_b2, out_w, out_b, g, c0);
    k_wprep<<<256, 256, 0, stream>>>(lin_w, v_w, f_w1, wcat_h, wcat_l, f1_h, f1_l);
    k_mfma_dual<<<512, 512, 0, stream>>>(data, wcat_h, wcat_l, v_b, x, tmat);
    k_scores<<<BN_TOT / 4, 256, 0, stream>>>(x, att_i, att_j, eemi, eemj, ni, nj);
    k_count<<<(E_ + 255) / 256, 256, 0, stream>>>(ei, offs);
    k_scan<<<1, 1024, 0, stream>>>(offs);
    k_scatter<<<(E_ + 255) / 256, 256, 0, stream>>>(ei, offs, cursor, csr_src);
    k_edge_w<<<BN_TOT / 4, 256, 0, stream>>>(ni, nj, offs, csr_src, exbuf, selfex, denomv);
    k_spmm<<<BN_TOT / 4, 256, 0, stream>>>(x, offs, csr_src, exbuf, selfex, denomv, gnn_bias, agg);
    k_bn_part<<<1024, 256, 0, stream>>>(agg, partials);
    k_bn_fin2<<<1, 1024, 0, stream>>>(partials, bn_gamma, bn_beta, scale, shift);
    k_mfma_fusion<<<512, 512, 0, stream>>>(agg, tmat, f1_h, f1_l, f_b1, scale, shift, g, c0, out);
}

// Round 7
// 201.656 us; speedup vs baseline: 2.5836x; 1.0709x over previous
//
#include <hip/hip_runtime.h>
#include <math.h>

constexpr int B_ = 64;
constexpr int N_ = 1000;
constexpr int D_ = 128;
constexpr int E_ = 20000;
constexpr int BN_TOT = B_ * N_;
constexpr float BN_EPS = 1e-5f;
constexpr float NEG_SLOPE = 0.2f;

typedef __attribute__((ext_vector_type(8))) __bf16 bf16x8;
typedef __attribute__((ext_vector_type(4))) float f32x4;
typedef __attribute__((ext_vector_type(2))) float f32x2;

__device__ __forceinline__ float leaky(float a) { return a >= 0.f ? a : NEG_SLOPE * a; }

__device__ __forceinline__ void split8(const float* v, bf16x8& h, bf16x8& l) {
#pragma unroll
    for (int j = 0; j < 8; ++j) {
        __bf16 hh = (__bf16)v[j];
        h[j] = hh;
        l[j] = (__bf16)(v[j] - (float)hh);
    }
}

// ---------------- small precompute kernels ----------------

__global__ void k_zero(int* base) {
    int i = threadIdx.x;
    for (int k = i; k < 2304; k += 256) base[k] = 0;
}

__global__ __launch_bounds__(64) void k_emb_scores(const float* __restrict__ emb,
                                                   const float* __restrict__ att_em_i,
                                                   const float* __restrict__ att_em_j,
                                                   float* __restrict__ eemi,
                                                   float* __restrict__ eemj) {
    int n = blockIdx.x;
    int lane = threadIdx.x;
    const float* er = emb + (size_t)n * D_;
    float e0 = er[lane], e1 = er[lane + 64];
    float si = e0 * att_em_i[lane] + e1 * att_em_i[lane + 64];
    float sj = e0 * att_em_j[lane] + e1 * att_em_j[lane + 64];
    for (int off = 32; off > 0; off >>= 1) {
        si += __shfl_down(si, off);
        sj += __shfl_down(sj, off);
    }
    if (lane == 0) { eemi[n] = si; eemj[n] = sj; }
}

__global__ void k_gvec(const float* __restrict__ f_w2, const float* __restrict__ f_b2,
                       const float* __restrict__ out_w, const float* __restrict__ out_b,
                       float* __restrict__ g, float* __restrict__ c0) {
    int j = threadIdx.x;  // 128
    float s = 0.f;
    for (int k = 0; k < D_; ++k) s += out_w[k] * f_w2[k * D_ + j];
    g[j] = s;
    if (j == 0) {
        float c = out_b[0];
        for (int k = 0; k < D_; ++k) c += out_w[k] * f_b2[k];
        *c0 = c;
    }
}

// split weights into bf16 hi/lo: wcat[256][128] = [lin_w ; v_w], f1[128][256] = f_w1
__global__ void k_wprep(const float* __restrict__ lin_w, const float* __restrict__ v_w,
                        const float* __restrict__ f_w1,
                        __bf16* __restrict__ wcat_h, __bf16* __restrict__ wcat_l,
                        __bf16* __restrict__ f1_h, __bf16* __restrict__ f1_l) {
    int i = blockIdx.x * 256 + threadIdx.x;  // 65536 total
    if (i < 32768) {
        float v = (i < 16384) ? lin_w[i] : v_w[i - 16384];
        __bf16 h = (__bf16)v;
        wcat_h[i] = h;
        wcat_l[i] = (__bf16)(v - (float)h);
    } else {
        int j = i - 32768;
        float v = f_w1[j];
        __bf16 h = (__bf16)v;
        f1_h[j] = h;
        f1_l[j] = (__bf16)(v - (float)h);
    }
}

// ---------------- MFMA dual GEMM: [x | t] = data @ [lin_w ; v_w]^T (+v_b on t half) ----------
__global__ __launch_bounds__(512) void k_mfma_dual(const float* __restrict__ data,
                                                   const __bf16* __restrict__ wcat_h,
                                                   const __bf16* __restrict__ wcat_l,
                                                   const float* __restrict__ v_b,
                                                   float* __restrict__ x,
                                                   float* __restrict__ tmat) {
    const int tid = threadIdx.x;
    const int w = tid >> 6;
    const int l = tid & 63;
    bf16x8 Bh[2][4], Bl[2][4];
#pragma unroll
    for (int nt = 0; nt < 2; ++nt) {
        const int n = w * 32 + nt * 16 + (l & 15);
#pragma unroll
        for (int kk = 0; kk < 4; ++kk) {
            const int k = kk * 32 + (l >> 4) * 8;
            Bh[nt][kk] = *(const bf16x8*)&wcat_h[n * D_ + k];
            Bl[nt][kk] = *(const bf16x8*)&wcat_l[n * D_ + k];
        }
    }
    float vb[2] = {0.f, 0.f};
    if (w >= 4) {
#pragma unroll
        for (int nt = 0; nt < 2; ++nt) vb[nt] = v_b[w * 32 + nt * 16 + (l & 15) - 128];
    }
    __shared__ __align__(16) __bf16 dh[32 * D_];
    __shared__ __align__(16) __bf16 dl[32 * D_];
    const int srow = tid >> 4;
    const int skq = (tid & 15) * 8;
    const int sidx = srow * D_ + (skq ^ ((srow & 7) * 8));
    const int nchunks = BN_TOT / 32;
    for (int ch = blockIdx.x; ch < nchunks; ch += gridDim.x) {
        const int row0 = ch * 32;
        {
            const float* src = data + (size_t)(row0 + srow) * D_ + skq;
            float v[8];
            float4 p0 = *(const float4*)src;
            float4 p1 = *(const float4*)(src + 4);
            v[0] = p0.x; v[1] = p0.y; v[2] = p0.z; v[3] = p0.w;
            v[4] = p1.x; v[5] = p1.y; v[6] = p1.z; v[7] = p1.w;
            bf16x8 hv, lv;
            split8(v, hv, lv);
            *(bf16x8*)&dh[sidx] = hv;
            *(bf16x8*)&dl[sidx] = lv;
        }
        __syncthreads();
        f32x4 acc[2][2];
#pragma unroll
        for (int mt = 0; mt < 2; ++mt)
#pragma unroll
            for (int nt = 0; nt < 2; ++nt) acc[mt][nt] = (f32x4){0.f, 0.f, 0.f, 0.f};
#pragma unroll
        for (int mt = 0; mt < 2; ++mt) {
#pragma unroll
            for (int kk = 0; kk < 4; ++kk) {
                const int ai = (mt * 16 + (l & 15)) * D_ + ((kk * 32 + (l >> 4) * 8) ^ ((l & 7) * 8));
                bf16x8 ah = *(const bf16x8*)&dh[ai];
                bf16x8 al = *(const bf16x8*)&dl[ai];
#pragma unroll
                for (int nt = 0; nt < 2; ++nt) {
                    acc[mt][nt] = __builtin_amdgcn_mfma_f32_16x16x32_bf16(ah, Bh[nt][kk], acc[mt][nt], 0, 0, 0);
                    acc[mt][nt] = __builtin_amdgcn_mfma_f32_16x16x32_bf16(ah, Bl[nt][kk], acc[mt][nt], 0, 0, 0);
                    acc[mt][nt] = __builtin_amdgcn_mfma_f32_16x16x32_bf16(al, Bh[nt][kk], acc[mt][nt], 0, 0, 0);
                }
            }
        }
#pragma unroll
        for (int mt = 0; mt < 2; ++mt) {
#pragma unroll
            for (int nt = 0; nt < 2; ++nt) {
                const int col = w * 32 + nt * 16 + (l & 15);
                const int rg = row0 + mt * 16 + (l >> 4) * 4;
                if (w < 4) {
#pragma unroll
                    for (int r = 0; r < 4; ++r)
                        x[(size_t)(rg + r) * D_ + col] = acc[mt][nt][r];
                } else {
                    const int c2 = col - 128;
#pragma unroll
                    for (int r = 0; r < 4; ++r)
                        tmat[(size_t)(rg + r) * D_ + c2] = acc[mt][nt][r] + vb[nt];
                }
            }
        }
        __syncthreads();
    }
}

// ---------------- node attention scores + packed-bf16 x copy ----------------
__global__ __launch_bounds__(256) void k_scores(const float* __restrict__ x,
                                                const float* __restrict__ att_i,
                                                const float* __restrict__ att_j,
                                                const float* __restrict__ eemi,
                                                const float* __restrict__ eemj,
                                                float* __restrict__ ni, float* __restrict__ nj,
                                                unsigned int* __restrict__ xb) {
    const int wid = threadIdx.x >> 6;
    const int lane = threadIdx.x & 63;
    const int row = blockIdx.x * 4 + wid;
    f32x2 xv = ((const f32x2*)x)[(size_t)row * 64 + lane];
    f32x2 ai = ((const f32x2*)att_i)[lane];
    f32x2 aj = ((const f32x2*)att_j)[lane];
    float si = xv.x * ai.x + xv.y * ai.y;
    float sj = xv.x * aj.x + xv.y * aj.y;
    // packed bf16 copy for the spmm gather (halves gather bytes; fits L2)
    {
        __bf16 bx = (__bf16)xv.x, by = (__bf16)xv.y;
        unsigned int ux = *(const unsigned short*)&bx;
        unsigned int uy = *(const unsigned short*)&by;
        xb[(size_t)row * 64 + lane] = ux | (uy << 16);
    }
    for (int off = 32; off > 0; off >>= 1) {
        si += __shfl_down(si, off);
        sj += __shfl_down(sj, off);
    }
    if (lane == 0) {
        int n = row % N_;
        ni[row] = si + eemi[n];
        nj[row] = sj + eemj[n];
    }
}

// ---------------- CSR build ----------------
__global__ void k_count(const int* __restrict__ ei, int* __restrict__ offs) {
    int e = blockIdx.x * blockDim.x + threadIdx.x;
    if (e < E_) atomicAdd(&offs[ei[E_ + e] + 1], 1);
}

__global__ __launch_bounds__(1024) void k_scan(int* __restrict__ offs) {
    __shared__ int s[N_ + 1];
    int tid = threadIdx.x;
    if (tid <= N_) s[tid] = offs[tid];
    __syncthreads();
    for (int off = 1; off <= N_; off <<= 1) {
        int v = 0;
        if (tid <= N_) { v = s[tid]; if (tid >= off) v += s[tid - off]; }
        __syncthreads();
        if (tid <= N_) s[tid] = v;
        __syncthreads();
    }
    if (tid <= N_) offs[tid] = s[tid];
}

__global__ void k_scatter(const int* __restrict__ ei, const int* __restrict__ offs,
                          int* __restrict__ cursor, int* __restrict__ csr_src) {
    int e = blockIdx.x * blockDim.x + threadIdx.x;
    if (e < E_) {
        int dn = ei[E_ + e];
        int pos = offs[dn] + atomicAdd(&cursor[dn], 1);
        csr_src[pos] = ei[e];
    }
}

// ---------------- edge softmax: one WAVE per (b,i) ----------------
__global__ __launch_bounds__(256) void k_edge_w(const float* __restrict__ ni,
                                                const float* __restrict__ nj,
                                                const int* __restrict__ offs,
                                                const int* __restrict__ csr_src,
                                                float* __restrict__ exbuf,
                                                float* __restrict__ selfex,
                                                float* __restrict__ denomv) {
    const int wid = threadIdx.x >> 6;
    const int lane = threadIdx.x & 63;
    const int bid = blockIdx.x * 4 + wid;
    const int b = bid / N_;
    const int i = bid - b * N_;
    const int base = b * N_;
    const int e0 = offs[i], e1 = offs[i + 1];
    const float nii = ni[bid];
    const float aself = leaky(nii + nj[bid]);
    float amax = aself;
    for (int e = e0 + lane; e < e1; e += 64) {
        int s = csr_src[e];
        amax = fmaxf(amax, leaky(nii + nj[base + s]));
    }
    for (int off = 32; off > 0; off >>= 1) amax = fmaxf(amax, __shfl_xor(amax, off));
    float sum = 0.f;
    if (lane == 0) {
        float se = __expf(aself - amax);
        selfex[bid] = se;
        sum = se;
    }
    for (int e = e0 + lane; e < e1; e += 64) {
        int s = csr_src[e];
        float ex = __expf(leaky(nii + nj[base + s]) - amax);
        exbuf[(size_t)b * E_ + e] = ex;
        sum += ex;
    }
    for (int off = 32; off > 0; off >>= 1) sum += __shfl_xor(sum, off);
    if (lane == 0) denomv[bid] = sum;
}

// ---------------- SpMM gather-aggregate: wave/segment, bf16 payload, NT agg store ----------
__global__ __launch_bounds__(256) void k_spmm(const unsigned int* __restrict__ xb,
                                              const int* __restrict__ offs,
                                              const int* __restrict__ csr_src,
                                              const float* __restrict__ exbuf,
                                              const float* __restrict__ selfex,
                                              const float* __restrict__ denomv,
                                              const float* __restrict__ gnn_bias,
                                              float* __restrict__ agg) {
    constexpr int CAP = 128;
    __shared__ int s_lds[4][CAP];
    __shared__ float w_lds[4][CAP];
    // 16000 blocks = 8 XCD * 2000; each XCD works a contiguous 8-batch slice (bf16 x = 2 MB, L2-fit)
    const int swz = (blockIdx.x & 7) * 2000 + (blockIdx.x >> 3);
    const int w = threadIdx.x >> 6;     // wave id = segment within block
    const int l = threadIdx.x & 63;     // lane = 2 channels (packed bf16 pair)
    const int bid = swz * 4 + w;
    const int b = bid / N_;
    const int i = bid - b * N_;
    const int base = b * N_;
    const int e0 = offs[i];
    const int deg = offs[i + 1] - e0;
    const int stg = deg < CAP ? deg : CAP;
    for (int k = l; k < stg; k += 64) {
        s_lds[w][k] = csr_src[e0 + k];
        w_lds[w][k] = exbuf[(size_t)b * E_ + e0 + k];
    }
    __syncthreads();
    float accx, accy;
    {
        float se = selfex[bid];
        unsigned int u = xb[(size_t)bid * 64 + l];
        accx = se * __uint_as_float(u << 16);
        accy = se * __uint_as_float(u & 0xffff0000u);
    }
    int k = 0;
    for (; k + 8 <= stg; k += 8) {
        unsigned int u[8];
        float wg[8];
#pragma unroll
        for (int j = 0; j < 8; ++j) {
            int s = s_lds[w][k + j];
            wg[j] = w_lds[w][k + j];
            u[j] = xb[(size_t)(base + s) * 64 + l];
        }
#pragma unroll
        for (int j = 0; j < 8; ++j) {
            accx += wg[j] * __uint_as_float(u[j] << 16);
            accy += wg[j] * __uint_as_float(u[j] & 0xffff0000u);
        }
    }
    for (; k < stg; ++k) {
        int s = s_lds[w][k];
        float wg = w_lds[w][k];
        unsigned int u = xb[(size_t)(base + s) * 64 + l];
        accx += wg * __uint_as_float(u << 16);
        accy += wg * __uint_as_float(u & 0xffff0000u);
    }
    for (int e = e0 + CAP; e < e0 + deg; ++e) {   // overflow fallback
        int s = csr_src[e];
        float wg = exbuf[(size_t)b * E_ + e];
        unsigned int u = xb[(size_t)(base + s) * 64 + l];
        accx += wg * __uint_as_float(u << 16);
        accy += wg * __uint_as_float(u & 0xffff0000u);
    }
    const float dn = 1.f / denomv[bid];
    f32x2 gb = ((const f32x2*)gnn_bias)[l];
    f32x2 o;
    o.x = accx * dn + gb.x;
    o.y = accy * dn + gb.y;
    // nontemporal: don't let 32 MB of streaming writes evict the x-slice from L2
    __builtin_nontemporal_store(o, (f32x2*)agg + (size_t)bid * 64 + l);
}

// ---------------- BatchNorm statistics: two-stage ----------------
__global__ __launch_bounds__(256) void k_bn_part(const float* __restrict__ agg,
                                                 float* __restrict__ partials) {
    const int g = threadIdx.x >> 5;
    const int c4 = threadIdx.x & 31;
    f32x4 s = (f32x4){0.f, 0.f, 0.f, 0.f};
    f32x4 q = (f32x4){0.f, 0.f, 0.f, 0.f};
    for (int r = blockIdx.x * 8 + g; r < BN_TOT; r += 8192) {
        float4 v = *(const float4*)&agg[(size_t)r * D_ + c4 * 4];
        s.x += v.x; s.y += v.y; s.z += v.z; s.w += v.w;
        q.x += v.x * v.x; q.y += v.y * v.y; q.z += v.z * v.z; q.w += v.w * v.w;
    }
    __shared__ f32x4 ls[8][32];
    __shared__ f32x4 lq[8][32];
    ls[g][c4] = s;
    lq[g][c4] = q;
    __syncthreads();
    if (threadIdx.x < 32) {
        f32x4 ts = ls[0][threadIdx.x];
        f32x4 tq = lq[0][threadIdx.x];
#pragma unroll
        for (int gg = 1; gg < 8; ++gg) {
            f32x4 a = ls[gg][threadIdx.x];
            f32x4 b = lq[gg][threadIdx.x];
            ts.x += a.x; ts.y += a.y; ts.z += a.z; ts.w += a.w;
            tq.x += b.x; tq.y += b.y; tq.z += b.z; tq.w += b.w;
        }
        f32x4* p = (f32x4*)partials + (size_t)blockIdx.x * 64;
        p[threadIdx.x] = ts;
        p[32 + threadIdx.x] = tq;
    }
}

__global__ __launch_bounds__(1024) void k_bn_fin2(const float* __restrict__ partials,
                                                  const float* __restrict__ gamma,
                                                  const float* __restrict__ beta,
                                                  float* __restrict__ scale,
                                                  float* __restrict__ shift) {
    const int d = threadIdx.x & 127;
    const int part = threadIdx.x >> 7;
    float s = 0.f, q = 0.f;
    for (int blk = part * 128; blk < part * 128 + 128; ++blk) {
        s += partials[(size_t)blk * 256 + d];
        q += partials[(size_t)blk * 256 + 128 + d];
    }
    __shared__ float lss[8][128];
    __shared__ float lqq[8][128];
    lss[part][d] = s;
    lqq[part][d] = q;
    __syncthreads();
    if (threadIdx.x < 128) {
        float ts = 0.f, tq = 0.f;
#pragma unroll
        for (int p = 0; p < 8; ++p) { ts += lss[p][d]; tq += lqq[p][d]; }
        float mu = ts * (1.f / BN_TOT);
        float var = tq * (1.f / BN_TOT) - mu * mu;
        float sc = gamma[d] * rsqrtf(var + BN_EPS);
        scale[d] = sc;
        shift[d] = beta[d] - mu * sc;
    }
}

// ---------------- MFMA fusion ----------------
__global__ __launch_bounds__(512) void k_mfma_fusion(const float* __restrict__ agg,
                                                     const float* __restrict__ tmat,
                                                     const __bf16* __restrict__ f1_h,
                                                     const __bf16* __restrict__ f1_l,
                                                     const float* __restrict__ f_b1,
                                                     const float* __restrict__ scale,
                                                     const float* __restrict__ shift,
                                                     const float* __restrict__ g,
                                                     const float* __restrict__ c0p,
                                                     float* __restrict__ out) {
    const int tid = threadIdx.x;
    const int w = tid >> 6;
    const int l = tid & 63;
    const float c0v = *c0p;
    bf16x8 Fh[8], Fl[8];
    const int ncol = w * 16 + (l & 15);
#pragma unroll
    for (int kk = 0; kk < 8; ++kk) {
        const int k = kk * 32 + (l >> 4) * 8;
        Fh[kk] = *(const bf16x8*)&f1_h[ncol * 256 + k];
        Fl[kk] = *(const bf16x8*)&f1_l[ncol * 256 + k];
    }
    const float b1c = f_b1[ncol];
    const float gc = g[ncol];
    __shared__ __align__(16) __bf16 ch_[32 * 256];
    __shared__ __align__(16) __bf16 cl_[32 * 256];
    __shared__ float part[8][32];
    const int srow = tid >> 4;
    const int scb = (tid & 15) * 16;
    const bool isagg = scb < 128;
    float4 sc4[4], sh4[4];
    if (isagg) {
#pragma unroll
        for (int q = 0; q < 4; ++q) {
            sc4[q] = *(const float4*)&scale[scb + q * 4];
            sh4[q] = *(const float4*)&shift[scb + q * 4];
        }
    }
    const int nchunks = BN_TOT / 32;
    for (int chk = blockIdx.x; chk < nchunks; chk += gridDim.x) {
        const int row0 = chk * 32;
        {
            const float* srcp = isagg ? (agg + (size_t)(row0 + srow) * D_ + scb)
                                      : (tmat + (size_t)(row0 + srow) * D_ + (scb - 128));
            float v[16];
#pragma unroll
            for (int q = 0; q < 4; ++q) {
                float4 p = *(const float4*)(srcp + q * 4);
                if (isagg) {
                    p.x = fmaxf(p.x * sc4[q].x + sh4[q].x, 0.f);
                    p.y = fmaxf(p.y * sc4[q].y + sh4[q].y, 0.f);
                    p.z = fmaxf(p.z * sc4[q].z + sh4[q].z, 0.f);
                    p.w = fmaxf(p.w * sc4[q].w + sh4[q].w, 0.f);
                }
                v[q * 4 + 0] = p.x; v[q * 4 + 1] = p.y; v[q * 4 + 2] = p.z; v[q * 4 + 3] = p.w;
            }
#pragma unroll
            for (int hh = 0; hh < 2; ++hh) {
                bf16x8 hv, lv;
                split8(v + hh * 8, hv, lv);
                const int c = scb + hh * 8;
                const int idx = srow * 256 + (c ^ ((srow & 7) * 8));
                *(bf16x8*)&ch_[idx] = hv;
                *(bf16x8*)&cl_[idx] = lv;
            }
        }
        __syncthreads();
#pragma unroll
        for (int mt = 0; mt < 2; ++mt) {
            f32x4 acc = (f32x4){0.f, 0.f, 0.f, 0.f};
#pragma unroll
            for (int kk = 0; kk < 8; ++kk) {
                const int ai = (mt * 16 + (l & 15)) * 256 + ((kk * 32 + (l >> 4) * 8) ^ ((l & 7) * 8));
                bf16x8 ah = *(const bf16x8*)&ch_[ai];
                bf16x8 al = *(const bf16x8*)&cl_[ai];
                acc = __builtin_amdgcn_mfma_f32_16x16x32_bf16(ah, Fh[kk], acc, 0, 0, 0);
                acc = __builtin_amdgcn_mfma_f32_16x16x32_bf16(ah, Fl[kk], acc, 0, 0, 0);
                acc = __builtin_amdgcn_mfma_f32_16x16x32_bf16(al, Fh[kk], acc, 0, 0, 0);
            }
            float p[4];
#pragma unroll
            for (int r = 0; r < 4; ++r) p[r] = fmaxf(acc[r] + b1c, 0.f) * gc;
#pragma unroll
            for (int r = 0; r < 4; ++r) {
                p[r] += __shfl_xor(p[r], 1);
                p[r] += __shfl_xor(p[r], 2);
                p[r] += __shfl_xor(p[r], 4);
                p[r] += __shfl_xor(p[r], 8);
            }
            if ((l & 15) == 0) {
#pragma unroll
                for (int r = 0; r < 4; ++r) part[w][mt * 16 + (l >> 4) * 4 + r] = p[r];
            }
        }
        __syncthreads();
        if (tid < 32) {
            float s = c0v;
#pragma unroll
            for (int ww = 0; ww < 8; ++ww) s += part[ww][tid];
            out[row0 + tid] = s;
        }
        __syncthreads();
    }
}

// ---------------- launch ----------------
extern "C" void kernel_launch(void* const* d_in, const int* in_sizes, int n_in,
                              void* d_out, int out_size, void* d_ws, size_t ws_size,
                              hipStream_t stream) {
    const float* data     = (const float*)d_in[0];
    const int*   ei       = (const int*)d_in[1];
    const float* emb      = (const float*)d_in[2];
    const float* lin_w    = (const float*)d_in[3];
    const float* att_i    = (const float*)d_in[4];
    const float* att_j    = (const float*)d_in[5];
    const float* att_em_i = (const float*)d_in[6];
    const float* att_em_j = (const float*)d_in[7];
    const float* gnn_bias = (const float*)d_in[8];
    const float* bn_gamma = (const float*)d_in[9];
    const float* bn_beta  = (const float*)d_in[10];
    // q_w,q_b,k_w,k_b,temperature dead (W=1 -> softmax over single element -> attn==1)
    const float* v_w      = (const float*)d_in[15];
    const float* v_b      = (const float*)d_in[16];
    const float* f_w1     = (const float*)d_in[18];
    const float* f_b1     = (const float*)d_in[19];
    const float* f_w2     = (const float*)d_in[20];
    const float* f_b2     = (const float*)d_in[21];
    const float* out_w    = (const float*)d_in[22];
    const float* out_b    = (const float*)d_in[23];
    float* out = (float*)d_out;

    float* ws = (float*)d_ws;
    float* x      = ws;                                 // BN*D
    float* tmat   = x + (size_t)BN_TOT * D_;            // BN*D
    float* agg    = tmat + (size_t)BN_TOT * D_;         // BN*D
    float* ni     = agg + (size_t)BN_TOT * D_;          // BN
    float* nj     = ni + BN_TOT;                        // BN
    float* eemi   = nj + BN_TOT;                        // N
    float* eemj   = eemi + N_;                          // N
    float* g      = eemj + N_;                          // D
    float* c0     = g + D_;                             // 1 (pad 8)
    float* scale  = c0 + 8;                             // D
    float* shift  = scale + D_;                         // D
    int* offs     = (int*)(shift + D_);                 // 1024 [zeroed]
    int* cursor   = offs + 1024;                        // 1024 [zeroed]
    float* bn_sum = (float*)(cursor + 1024);            // 128  [zeroed, unused now]
    float* bn_sq  = bn_sum + D_;                        // 128  [zeroed, unused now]
    int* csr_src  = (int*)(bn_sq + D_);                 // E
    float* exbuf  = (float*)(csr_src + E_);             // B*E
    float* selfex = exbuf + (size_t)B_ * E_;            // BN
    float* denomv = selfex + BN_TOT;                    // BN
    __bf16* wcat_h = (__bf16*)(denomv + BN_TOT);        // 256*128
    __bf16* wcat_l = wcat_h + 256 * 128;                // 256*128
    __bf16* f1_h   = wcat_l + 256 * 128;                // 128*256
    __bf16* f1_l   = f1_h + 128 * 256;                  // 128*256
    float* partials = (float*)(f1_l + 128 * 256);       // 1024*256 floats = 1 MB
    unsigned int* xb = (unsigned int*)(partials + 1024 * 256);  // BN*64 uints (packed bf16 x)

    k_zero<<<1, 256, 0, stream>>>(offs);
    k_emb_scores<<<N_, 64, 0, stream>>>(emb, att_em_i, att_em_j, eemi, eemj);
    k_gvec<<<1, 128, 0, stream>>>(f_w2, f_b2, out_w, out_b, g, c0);
    k_wprep<<<256, 256, 0, stream>>>(lin_w, v_w, f_w1, wcat_h, wcat_l, f1_h, f1_l);
    k_mfma_dual<<<512, 512, 0, stream>>>(data, wcat_h, wcat_l, v_b, x, tmat);
    k_scores<<<BN_TOT / 4, 256, 0, stream>>>(x, att_i, att_j, eemi, eemj, ni, nj, xb);
    k_count<<<(E_ + 255) / 256, 256, 0, stream>>>(ei, offs);
    k_scan<<<1, 1024, 0, stream>>>(offs);
    k_scatter<<<(E_ + 255) / 256, 256, 0, stream>>>(ei, offs, cursor, csr_src);
    k_edge_w<<<BN_TOT / 4, 256, 0, stream>>>(ni, nj, offs, csr_src, exbuf, selfex, denomv);
    k_spmm<<<BN_TOT / 4, 256, 0, stream>>>(xb, offs, csr_src, exbuf, selfex, denomv, gnn_bias, agg);
    k_bn_part<<<1024, 256, 0, stream>>>(agg, partials);
    k_bn_fin2<<<1, 1024, 0, stream>>>(partials, bn_gamma, bn_beta, scale, shift);
    k_mfma_fusion<<<512, 512, 0, stream>>>(agg, tmat, f1_h, f1_l, f_b1, scale, shift, g, c0, out);
}